// Round 4
// baseline (1951.020 us; speedup 1.0000x reference)
//
#include <hip/hip_runtime.h>

#define N_NODES 50000
#define N_EDGES 1600000

// bucket geometry
#define EPB 8192                          // edges per chunk-block
#define NB1 ((N_EDGES + EPB - 1) / EPB)   // 196 chunks
#define NPB 64                            // nodes per bucket
#define NBK ((N_NODES + NPB - 1) / NPB)   // 782 buckets
#define TBL (NBK * NB1)                   // 153272 table entries

typedef unsigned short ushort_t;
typedef __attribute__((ext_vector_type(8))) __bf16 bf16x8;
typedef __attribute__((ext_vector_type(4))) float  f32x4;

union FU { ushort_t s[8]; bf16x8 v; };

__device__ __forceinline__ ushort_t f2bf(float f) {
    union { float f; unsigned int i; } v; v.f = f;
    unsigned int r = v.i + 0x7fffu + ((v.i >> 16) & 1u);
    return (ushort_t)(r >> 16);
}
__device__ __forceinline__ float leaky(float x, float s) { return x >= 0.f ? x : s * x; }

// ---------------- K0: x_t -> bf16 (1.6 MB, L2-resident for the gather in k_bscat/k_nodeB) ----
__global__ __launch_bounds__(256) void k_cvtx(const float* __restrict__ x_t,
                                              ushort_t* __restrict__ x_tb) {
    int i = blockIdx.x * 256 + threadIdx.x;          // one f32x4 (4 elems) per thread
    if (i < (N_NODES * 16) / 4) {
        f32x4 v = ((const f32x4*)x_t)[i];
        unsigned long long p = (unsigned long long)f2bf(v[0])
                             | ((unsigned long long)f2bf(v[1]) << 16)
                             | ((unsigned long long)f2bf(v[2]) << 32)
                             | ((unsigned long long)f2bf(v[3]) << 48);
        ((unsigned long long*)x_tb)[i] = p;
    }
}

// ---------------- K1: per-(bucket, chunk) histogram (LDS only) ----------------
__global__ __launch_bounds__(256) void k_bcount(const int* __restrict__ src, int* __restrict__ table) {
    __shared__ int cnt[NBK];
    const int t = threadIdx.x, blk = blockIdx.x;
    for (int i = t; i < NBK; i += 256) cnt[i] = 0;
    __syncthreads();
    const int base = blk * EPB;
    for (int i = t; i < EPB; i += 256) {
        int e = base + i;
        if (e < N_EDGES) atomicAdd(&cnt[src[e] >> 6], 1);   // NPB = 64
    }
    __syncthreads();
    for (int b = t; b < NBK; b += 256) table[b * NB1 + blk] = cnt[b];
}

// ---------------- K2: exclusive scan of flattened [bucket][chunk] table (+bnsum zero) --------
__global__ __launch_bounds__(256) void k_bscan(int* __restrict__ table, float* __restrict__ bnsum) {
    __shared__ int sums[256];
    const int t = threadIdx.x;
    if (t < 32) bnsum[t] = 0.f;
    const int SEG = (TBL + 255) / 256;
    const int s0 = t * SEG, s1 = (s0 + SEG < TBL) ? s0 + SEG : TBL;
    int sum = 0;
    for (int i = s0; i < s1; i++) sum += table[i];
    sums[t] = sum; __syncthreads();
    for (int off = 1; off < 256; off <<= 1) {
        int x = (t >= off) ? sums[t - off] : 0;
        __syncthreads(); sums[t] += x; __syncthreads();
    }
    int carry = sums[t] - sum;
    for (int i = s0; i < s1; i++) { int v = table[i]; table[i] = carry; carry += v; }
}

// ---------------- K3: edge-order record deposit ----------------
// Sequential src/tgt/ea reads (full-line); per-edge record = [tgt | node_local<<16] (4 B)
// + ea as bf16 (32 B), written into per-(bucket,chunk) runs -> L2 write-combined full lines.
// NO random >=64 B reads anywhere; the only gather left in the pipeline is x_tb (1.6 MB, L2).
__global__ __launch_bounds__(256) void k_bscat(const int* __restrict__ src, const int* __restrict__ tgt,
                                               const float* __restrict__ ea, const int* __restrict__ table,
                                               int* __restrict__ tnA, ushort_t* __restrict__ eaA) {
    __shared__ int cur[NBK];
    const int t = threadIdx.x, blk = blockIdx.x;
    for (int i = t; i < NBK; i += 256) cur[i] = table[i * NB1 + blk];
    __syncthreads();
    const int base = blk * EPB;
    for (int i = t; i < EPB; i += 256) {
        int e = base + i;
        if (e < N_EDGES) {
            int s = src[e];
            int pos = atomicAdd(&cur[s >> 6], 1);            // LDS atomic
            tnA[pos] = tgt[e] | ((s & (NPB - 1)) << 16);     // tgt < 2^16
            const f32x4* ep = (const f32x4*)(ea + (size_t)e * 16);
            f32x4 v0 = __builtin_nontemporal_load(ep);
            f32x4 v1 = __builtin_nontemporal_load(ep + 1);
            f32x4 v2 = __builtin_nontemporal_load(ep + 2);
            f32x4 v3 = __builtin_nontemporal_load(ep + 3);
            FU lo, hi;
            #pragma unroll
            for (int j = 0; j < 4; j++) {
                lo.s[j] = f2bf(v0[j]); lo.s[4 + j] = f2bf(v1[j]);
                hi.s[j] = f2bf(v2[j]); hi.s[4 + j] = f2bf(v3[j]);
            }
            *(bf16x8*)(eaA + (size_t)pos * 16)     = lo.v;
            *(bf16x8*)(eaA + (size_t)pos * 16 + 8) = hi.v;
        }
    }
}

// ---------------- K4: per-bucket edge-MLP + LDS moment accumulation + feature build ----------
// One block per bucket (782). Records read PERFECTLY SEQUENTIALLY; x_tb gather hits L2.
// Moments go to LDS f32 accumulators via ds_add_f32, feature index swizzled (f+node)&31
// so each node-group maps to distinct banks.
__global__ __launch_bounds__(256) void k_nodeB(
    const ushort_t* __restrict__ x_tb, const ushort_t* __restrict__ eaA, const int* __restrict__ tnA,
    const int* __restrict__ table,
    const float* __restrict__ w1a, const float* __restrict__ b1a,
    const float* __restrict__ w2a, const float* __restrict__ b2a,
    const float* __restrict__ x_s, const float* __restrict__ u,
    ushort_t* __restrict__ hcat)
{
    __shared__ float acc4[4][NPB][32];                  // 32 KB, swizzled feat idx
    __shared__ int   dcnt[NPB];
    __shared__ __align__(16) float h_lds[4][16][36];    // wave-private h slice (proven layout)
    const int t = threadIdx.x;
    const int w = t >> 6, L = t & 63, q = L >> 4, c = L & 15;

    for (int i = t; i < 4 * NPB * 32; i += 256) ((float*)acc4)[i] = 0.f;
    if (t < NPB) dcnt[t] = 0;

    // weight fragments (B-operand layout: col = c+16h, k = q*8+j) — identical to proven kernel
    bf16x8 B1[2], B2[2];
    #pragma unroll
    for (int h = 0; h < 2; h++) {
        FU u1, u2;
        #pragma unroll
        for (int j = 0; j < 8; j++) {
            int kk = q * 8 + j, nn = c + 16 * h;
            u1.s[j] = f2bf(w1a[kk * 32 + nn]);
            u2.s[j] = f2bf(w2a[kk * 32 + nn]);
        }
        B1[h] = u1.v; B2[h] = u2.v;
    }
    const float bias1[2] = { b1a[c], b1a[c + 16] };
    const float bias2[2] = { b2a[c], b2a[c + 16] };
    const f32x4 zero = { 0.f, 0.f, 0.f, 0.f };
    __syncthreads();

    const int b    = blockIdx.x;
    const int base = table[b * NB1];
    const int end  = (b < NBK - 1) ? table[(b + 1) * NB1] : N_EDGES;
    const int cntB = end - base;
    const int ntl  = (cntB + 15) >> 4;

    for (int tl = w; tl < ntl; tl += 4) {
        int row  = tl * 16 + c;
        int ridx = row < cntB ? row : cntB - 1;          // dup rows masked below
        int pos  = base + ridx;
        FU af;
        if (q < 2) {
            int tg = tnA[pos] & 0xFFFF;
            __builtin_memcpy(&af.v, x_tb + (size_t)tg * 16 + q * 8, 16);
        } else {
            __builtin_memcpy(&af.v, eaA + (size_t)pos * 16 + (q - 2) * 8, 16);
        }

        f32x4 a0 = __builtin_amdgcn_mfma_f32_16x16x32_bf16(af.v, B1[0], zero, 0, 0, 0);
        f32x4 a1 = __builtin_amdgcn_mfma_f32_16x16x32_bf16(af.v, B1[1], zero, 0, 0, 0);
        #pragma unroll
        for (int r = 0; r < 4; r++) {
            h_lds[w][q * 4 + r][c]      = leaky(a0[r] + bias1[0], 0.1f);
            h_lds[w][q * 4 + r][c + 16] = leaky(a1[r] + bias1[1], 0.1f);
        }
        __asm__ volatile("s_waitcnt lgkmcnt(0)" ::: "memory");

        float hv[8];
        __builtin_memcpy(&hv, &h_lds[w][c][q * 8], 32);
        FU hf;
        #pragma unroll
        for (int j = 0; j < 8; j++) hf.s[j] = f2bf(hv[j]);
        f32x4 m0 = __builtin_amdgcn_mfma_f32_16x16x32_bf16(hf.v, B2[0], zero, 0, 0, 0);
        f32x4 m1 = __builtin_amdgcn_mfma_f32_16x16x32_bf16(hf.v, B2[1], zero, 0, 0, 0);

        #pragma unroll
        for (int r = 0; r < 4; r++) {
            int rb = tl * 16 + q * 4 + r;
            if (rb < cntB) {
                int nl = tnA[base + rb] >> 16;           // node_local 0..63
                float m = m0[r] + bias2[0], mm = m * m;
                int fa = (c + nl) & 31;
                atomicAdd(&acc4[0][nl][fa], m);
                atomicAdd(&acc4[1][nl][fa], mm);
                atomicAdd(&acc4[2][nl][fa], mm * m);
                atomicAdd(&acc4[3][nl][fa], mm * mm);
                float x = m1[r] + bias2[1], xx = x * x;
                int fb = (c + 16 + nl) & 31;
                atomicAdd(&acc4[0][nl][fb], x);
                atomicAdd(&acc4[1][nl][fb], xx);
                atomicAdd(&acc4[2][nl][fb], xx * x);
                atomicAdd(&acc4[3][nl][fb], xx * xx);
                if (c == 0) atomicAdd(&dcnt[nl], 1);
            }
        }
        // next tile's h_lds writes ordered after this tile's reads (per-wave in-order DS)
    }
    __syncthreads();

    // finalize stats: (node, feat) pairs, 2048 / 256 threads = 8 each
    #pragma unroll
    for (int i = 0; i < 8; i++) {
        int nl = (t >> 5) + i * 8, f = t & 31;
        int n = b * NPB + nl;
        if (n < N_NODES) {
            float denom = fmaxf((float)dcnt[nl], 1.f);
            int fi = (f + nl) & 31;
            float s1 = acc4[0][nl][fi], s2 = acc4[1][nl][fi];
            float s3 = acc4[2][nl][fi], s4 = acc4[3][nl][fi];
            float mean = s1 / denom, m2r = s2 / denom, m3r = s3 / denom, m4r = s4 / denom;
            float var  = leaky(m2r - mean * mean, 0.01f);
            float stdv = sqrtf(var + 1e-6f);
            float e3   = m3r - 3.f * mean * m2r + 2.f * mean * mean * mean;
            float skew = e3 / (stdv * stdv * stdv);
            float e4   = m4r - 4.f * mean * m3r + 6.f * mean * mean * m2r
                         - 3.f * mean * mean * mean * mean;
            float kurt = e4 / (stdv * stdv * stdv * stdv);
            size_t basep = (size_t)n * 160;
            hcat[basep + 16  + f] = f2bf(mean);
            hcat[basep + 48  + f] = f2bf(stdv);
            hcat[basep + 80  + f] = f2bf(skew);
            hcat[basep + 112 + f] = f2bf(kurt);
        }
    }
    // x_s and u sections: (node, pos) pairs, 1024 / 256 = 4 each
    #pragma unroll
    for (int i = 0; i < 4; i++) {
        int nl = (t >> 4) + i * 16, pos = t & 15;
        int n = b * NPB + nl;
        if (n < N_NODES) {
            size_t basep = (size_t)n * 160;
            hcat[basep + pos]       = f2bf(x_s[(size_t)n * 16 + pos]);
            hcat[basep + 144 + pos] = f2bf(u[pos]);
        }
    }
}

// ---------------- K5: GEMM1 [N,160]@[160,160] + bias + leaky -> h2 (bf16) ----------------
__global__ __launch_bounds__(256) void k_gemm1(const ushort_t* __restrict__ hcat,
                                               const float* __restrict__ w1b,
                                               const float* __restrict__ b1b,
                                               ushort_t* __restrict__ h2)
{
    __shared__ __align__(16) ushort_t W1T[160 * 168];
    int t = threadIdx.x;
    for (int i = t; i < 160 * 160; i += 256) { int k = i / 160, n = i % 160; W1T[n * 168 + k] = f2bf(w1b[i]); }
    __syncthreads();
    int w = t >> 6, L = t & 63, q = L >> 4, c = L & 15;
    const f32x4 zero = { 0.f, 0.f, 0.f, 0.f };
    for (int tile = blockIdx.x * 4 + w; tile < 3125 * 10; tile += gridDim.x * 4) {
        int rt = tile / 10, nt = tile % 10;
        int m = rt * 16 + c, n = nt * 16 + c;
        f32x4 acc = zero;
        #pragma unroll
        for (int ks = 0; ks < 5; ks++) {
            bf16x8 a; __builtin_memcpy(&a, hcat + (size_t)m * 160 + ks * 32 + q * 8, 16);
            bf16x8 b; __builtin_memcpy(&b, &W1T[n * 168 + ks * 32 + q * 8], 16);
            acc = __builtin_amdgcn_mfma_f32_16x16x32_bf16(a, b, acc, 0, 0, 0);
        }
        float bias = b1b[n];
        #pragma unroll
        for (int r = 0; r < 4; r++) {
            h2[(size_t)(rt * 16 + q * 4 + r) * 160 + n] = f2bf(leaky(acc[r] + bias, 0.1f));
        }
    }
}

// ---------------- K6: GEMM2 [N,160]@[160,16] + bias -> outpre (fp32) + BN partials ----------
__global__ __launch_bounds__(256) void k_gemm2(const ushort_t* __restrict__ h2,
                                               const float* __restrict__ w2b,
                                               const float* __restrict__ b2b,
                                               float* __restrict__ outpre, float* __restrict__ bnsum)
{
    __shared__ __align__(16) ushort_t W2T[16 * 168];
    int t = threadIdx.x;
    for (int i = t; i < 160 * 16; i += 256) { int k = i / 16, n = i % 16; W2T[n * 168 + k] = f2bf(w2b[i]); }
    __syncthreads();
    int w = t >> 6, L = t & 63, q = L >> 4, c = L & 15;
    const f32x4 zero = { 0.f, 0.f, 0.f, 0.f };
    float ps = 0.f, ps2 = 0.f;
    float bias = b2b[c];
    for (int rt = blockIdx.x * 4 + w; rt < 3125; rt += gridDim.x * 4) {
        int m = rt * 16 + c;
        f32x4 acc = zero;
        #pragma unroll
        for (int ks = 0; ks < 5; ks++) {
            bf16x8 a; __builtin_memcpy(&a, h2 + (size_t)m * 160 + ks * 32 + q * 8, 16);
            bf16x8 b; __builtin_memcpy(&b, &W2T[c * 168 + ks * 32 + q * 8], 16);
            acc = __builtin_amdgcn_mfma_f32_16x16x32_bf16(a, b, acc, 0, 0, 0);
        }
        #pragma unroll
        for (int r = 0; r < 4; r++) {
            float v = acc[r] + bias;
            outpre[(size_t)(rt * 16 + q * 4 + r) * 16 + c] = v;
            ps += v; ps2 += v * v;
        }
    }
    ps  += __shfl_xor(ps, 16);  ps  += __shfl_xor(ps, 32);
    ps2 += __shfl_xor(ps2, 16); ps2 += __shfl_xor(ps2, 32);
    if (q == 0) {
        unsafeAtomicAdd(&bnsum[c], ps);
        unsafeAtomicAdd(&bnsum[16 + c], ps2);
    }
}

// ---------------- K7: BatchNorm apply -> d_out (fp32) ----------------
__global__ __launch_bounds__(256) void k_bn(const float* __restrict__ outpre, const float* __restrict__ bnsum,
                                            const float* __restrict__ gamma, const float* __restrict__ beta,
                                            float* __restrict__ out)
{
    int i = blockIdx.x * 256 + threadIdx.x;
    int c = i & 15;
    float x = outpre[i];
    float mu = bnsum[c] * (1.f / N_NODES);
    float var = bnsum[16 + c] * (1.f / N_NODES) - mu * mu;
    out[i] = gamma[c] * (x - mu) * rsqrtf(var + 1e-5f) + beta[c];
}

// ---------------- launch ----------------
extern "C" void kernel_launch(void* const* d_in, const int* in_sizes, int n_in,
                              void* d_out, int out_size, void* d_ws, size_t ws_size,
                              hipStream_t stream) {
    const float* x_s  = (const float*)d_in[0];
    const float* x_t  = (const float*)d_in[1];
    const float* ea   = (const float*)d_in[2];
    const float* u    = (const float*)d_in[3];
    const float* w1a  = (const float*)d_in[4];
    const float* b1a  = (const float*)d_in[5];
    const float* w2a  = (const float*)d_in[6];
    const float* b2a  = (const float*)d_in[7];
    const float* w1b  = (const float*)d_in[8];
    const float* b1b  = (const float*)d_in[9];
    const float* w2b  = (const float*)d_in[10];
    const float* b2b  = (const float*)d_in[11];
    const float* gam  = (const float*)d_in[12];
    const float* bet  = (const float*)d_in[13];
    const int* eidx   = (const int*)d_in[14];
    const int* src = eidx;
    const int* tgt = eidx + N_EDGES;

    char* ws = (char*)d_ws;
    // workspace layout (bytes) — ws_size >= 138,001,536 proven; peak used ~101 MB.
    //   table  [0         ,   613,088)  int[153272]; k_bcount -> k_bscan -> k_bscat/k_nodeB
    //   bnsum  [  655,360 ,   655,488)  float[32]; zeroed in k_bscan
    //   outpre [  786,432 , 3,986,432)  float[800000]
    //   x_tb   [4,194,304 , 5,794,304)  bf16[50000*16]; k_cvtx -> k_nodeB
    //   tnA    [6,291,456 ,12,691,456)  int[1.6M] (tgt | node_local<<16); k_bscat -> k_nodeB
    //   eaA    [16,777,216,67,977,216)  bf16[1.6M*16]; k_bscat -> k_nodeB
    //   hcat   [68,157,440,84,157,440)  bf16[50000*160]; k_nodeB -> k_gemm1
    //   h2     [84,934,656,100,934,656) bf16[50000*160]; k_gemm1 -> k_gemm2
    const size_t OFF_TABLE  = 0;
    const size_t OFF_BNSUM  = 655360;
    const size_t OFF_OUTPRE = 786432;
    const size_t OFF_XTB    = 4194304;
    const size_t OFF_TNA    = 6291456;
    const size_t OFF_EAA    = 16777216;
    const size_t OFF_HCAT   = 68157440;
    const size_t OFF_H2     = 84934656;

    int*      table  = (int*)(ws + OFF_TABLE);
    float*    bnsum  = (float*)(ws + OFF_BNSUM);
    float*    outpre = (float*)(ws + OFF_OUTPRE);
    ushort_t* x_tb   = (ushort_t*)(ws + OFF_XTB);
    int*      tnA    = (int*)(ws + OFF_TNA);
    ushort_t* eaA    = (ushort_t*)(ws + OFF_EAA);
    ushort_t* hcat   = (ushort_t*)(ws + OFF_HCAT);
    ushort_t* h2     = (ushort_t*)(ws + OFF_H2);

    k_cvtx  <<<(N_NODES * 16 / 4 + 255) / 256, 256, 0, stream>>>(x_t, x_tb);
    k_bcount<<<NB1, 256, 0, stream>>>(src, table);
    k_bscan <<<1,   256, 0, stream>>>(table, bnsum);
    k_bscat <<<NB1, 256, 0, stream>>>(src, tgt, ea, table, tnA, eaA);
    k_nodeB <<<NBK, 256, 0, stream>>>(x_tb, eaA, tnA, table, w1a, b1a, w2a, b2a, x_s, u, hcat);
    k_gemm1 <<<1024, 256, 0, stream>>>(hcat, w1b, b1b, h2);
    k_gemm2 <<<512,  256, 0, stream>>>(h2, w2b, b2b, outpre, bnsum);
    k_bn    <<<(N_NODES * 16) / 256, 256, 0, stream>>>(outpre, bnsum, gam, bet, (float*)d_out);
}

// Round 5
// 696.625 us; speedup vs baseline: 2.8007x; 2.8007x over previous
//
#include <hip/hip_runtime.h>

#define N_NODES 50000
#define N_EDGES 1600000

// bucket geometry
#define EPB 8192                          // edges per chunk-block
#define NB1 ((N_EDGES + EPB - 1) / EPB)   // 196 chunks
#define NPB 64                            // nodes per bucket
#define NBK ((N_NODES + NPB - 1) / NPB)   // 782 buckets
#define TBL (NBK * NB1)                   // 153272 table entries
#define MAXB 4096                         // LDS capacity per bucket (mean 2048, sigma ~45)

typedef unsigned short ushort_t;
typedef __attribute__((ext_vector_type(8))) __bf16 bf16x8;
typedef __attribute__((ext_vector_type(4))) float  f32x4;

union FU { ushort_t s[8]; bf16x8 v; };

__device__ __forceinline__ ushort_t f2bf(float f) {
    union { float f; unsigned int i; } v; v.f = f;
    unsigned int r = v.i + 0x7fffu + ((v.i >> 16) & 1u);
    return (ushort_t)(r >> 16);
}
__device__ __forceinline__ float leaky(float x, float s) { return x >= 0.f ? x : s * x; }

// ---------------- K0: x_t -> bf16 (1.6 MB, L2-resident gather target) ----------------
__global__ __launch_bounds__(256) void k_cvtx(const float* __restrict__ x_t,
                                              ushort_t* __restrict__ x_tb) {
    int i = blockIdx.x * 256 + threadIdx.x;          // one f32x4 (4 elems) per thread
    if (i < (N_NODES * 16) / 4) {
        f32x4 v = ((const f32x4*)x_t)[i];
        unsigned long long p = (unsigned long long)f2bf(v[0])
                             | ((unsigned long long)f2bf(v[1]) << 16)
                             | ((unsigned long long)f2bf(v[2]) << 32)
                             | ((unsigned long long)f2bf(v[3]) << 48);
        ((unsigned long long*)x_tb)[i] = p;
    }
}

// ---------------- K1: per-(bucket, chunk) histogram (LDS int atomics only) ----------------
__global__ __launch_bounds__(256) void k_bcount(const int* __restrict__ src, int* __restrict__ table) {
    __shared__ int cnt[NBK];
    const int t = threadIdx.x, blk = blockIdx.x;
    for (int i = t; i < NBK; i += 256) cnt[i] = 0;
    __syncthreads();
    const int base = blk * EPB;
    for (int i = t; i < EPB; i += 256) {
        int e = base + i;
        if (e < N_EDGES) atomicAdd(&cnt[src[e] >> 6], 1);   // NPB = 64
    }
    __syncthreads();
    for (int b = t; b < NBK; b += 256) table[b * NB1 + blk] = cnt[b];
}

// ---------------- K2: exclusive scan of flattened [bucket][chunk] table (+bnsum zero) --------
__global__ __launch_bounds__(256) void k_bscan(int* __restrict__ table, float* __restrict__ bnsum) {
    __shared__ int sums[256];
    const int t = threadIdx.x;
    if (t < 32) bnsum[t] = 0.f;
    const int SEG = (TBL + 255) / 256;
    const int s0 = t * SEG, s1 = (s0 + SEG < TBL) ? s0 + SEG : TBL;
    int sum = 0;
    for (int i = s0; i < s1; i++) sum += table[i];
    sums[t] = sum; __syncthreads();
    for (int off = 1; off < 256; off <<= 1) {
        int x = (t >= off) ? sums[t - off] : 0;
        __syncthreads(); sums[t] += x; __syncthreads();
    }
    int carry = sums[t] - sum;
    for (int i = s0; i < s1; i++) { int v = table[i]; table[i] = carry; carry += v; }
}

// ---------------- K3: edge-order record deposit (proven round 4) ----------------
// Sequential src/tgt/ea reads; record = [tgt | node_local<<16] (4 B) + ea bf16 (32 B)
// written into per-(bucket,chunk) runs -> L2 write-combined full lines.
__global__ __launch_bounds__(256) void k_bscat(const int* __restrict__ src, const int* __restrict__ tgt,
                                               const float* __restrict__ ea, const int* __restrict__ table,
                                               int* __restrict__ tnA, ushort_t* __restrict__ eaA) {
    __shared__ int cur[NBK];
    const int t = threadIdx.x, blk = blockIdx.x;
    for (int i = t; i < NBK; i += 256) cur[i] = table[i * NB1 + blk];
    __syncthreads();
    const int base = blk * EPB;
    for (int i = t; i < EPB; i += 256) {
        int e = base + i;
        if (e < N_EDGES) {
            int s = src[e];
            int pos = atomicAdd(&cur[s >> 6], 1);            // LDS int atomic (native)
            tnA[pos] = tgt[e] | ((s & (NPB - 1)) << 16);     // tgt < 2^16
            const f32x4* ep = (const f32x4*)(ea + (size_t)e * 16);
            f32x4 v0 = __builtin_nontemporal_load(ep);
            f32x4 v1 = __builtin_nontemporal_load(ep + 1);
            f32x4 v2 = __builtin_nontemporal_load(ep + 2);
            f32x4 v3 = __builtin_nontemporal_load(ep + 3);
            FU lo, hi;
            #pragma unroll
            for (int j = 0; j < 4; j++) {
                lo.s[j] = f2bf(v0[j]); lo.s[4 + j] = f2bf(v1[j]);
                hi.s[j] = f2bf(v2[j]); hi.s[4 + j] = f2bf(v3[j]);
            }
            *(bf16x8*)(eaA + (size_t)pos * 16)     = lo.v;
            *(bf16x8*)(eaA + (size_t)pos * 16 + 8) = hi.v;
        }
    }
}

// ---------------- K4: per-bucket node-sort prologue + wave-per-node register moments --------
// One block per bucket. Prologue: LDS INT atomics (native ds_add, no CAS) build a
// node-sorted local perm + tgt table. Main loop: round-3's PROVEN register power-sum
// structure (no atomics at all); inputs pre-bf16 so no per-gather f2bf. Bucket's 72 KB
// record window is block-private -> each HBM line fetched once.
__global__ __launch_bounds__(256) void k_nodeF(
    const ushort_t* __restrict__ x_tb, const ushort_t* __restrict__ eaA, const int* __restrict__ tnA,
    const int* __restrict__ table,
    const float* __restrict__ w1a, const float* __restrict__ b1a,
    const float* __restrict__ w2a, const float* __restrict__ b2a,
    const float* __restrict__ x_s, const float* __restrict__ u,
    ushort_t* __restrict__ hcat)
{
    __shared__ ushort_t permL[MAXB];                    // node-sorted local indices
    __shared__ ushort_t tgL[MAXB];                      // tgt per local index
    __shared__ int cntL[NPB], scanL[NPB], curL[NPB];
    __shared__ __align__(16) float h_lds[4][16][36];    // wave-private h slice (proven)
    __shared__ ushort_t stat_lds[4][128];               // wave-private stats staging

    const int t = threadIdx.x;
    const int w = t >> 6, L = t & 63, q = L >> 4, c = L & 15;
    const int b = blockIdx.x;
    const int base  = table[b * NB1];
    const int end   = (b < NBK - 1) ? table[(b + 1) * NB1] : N_EDGES;
    const int cntB0 = end - base;
    const int cntB  = cntB0 < MAXB ? cntB0 : MAXB;      // safety clamp (never hit: +45 sigma)

    if (t < NPB) cntL[t] = 0;
    __syncthreads();
    for (int i = t; i < cntB; i += 256) {
        int v = tnA[base + i];
        tgL[i] = (ushort_t)(v & 0xFFFF);
        atomicAdd(&cntL[v >> 16], 1);                   // LDS int atomic
    }
    __syncthreads();
    if (t == 0) {
        int s = 0;
        for (int nl = 0; nl < NPB; nl++) { scanL[nl] = s; s += cntL[nl]; }
    }
    __syncthreads();
    if (t < NPB) curL[t] = scanL[t];
    __syncthreads();
    for (int i = t; i < cntB; i += 256) {
        int nl = tnA[base + i] >> 16;
        int loc = atomicAdd(&curL[nl], 1);              // LDS int atomic
        permL[loc] = (ushort_t)i;
    }

    // weight fragments (B-operand layout: col = c+16h, k = q*8+j) — proven layout
    bf16x8 B1[2], B2[2];
    #pragma unroll
    for (int h = 0; h < 2; h++) {
        FU u1, u2;
        #pragma unroll
        for (int j = 0; j < 8; j++) {
            int kk = q * 8 + j, nn = c + 16 * h;
            u1.s[j] = f2bf(w1a[kk * 32 + nn]);
            u2.s[j] = f2bf(w2a[kk * 32 + nn]);
        }
        B1[h] = u1.v; B2[h] = u2.v;
    }
    const float bias1[2] = { b1a[c], b1a[c + 16] };
    const float bias2[2] = { b2a[c], b2a[c + 16] };
    const f32x4 zero = { 0.f, 0.f, 0.f, 0.f };
    __syncthreads();                                    // perm/tgL visible to all waves

    for (int kn = 0; kn < 16; kn++) {
        const int nl = w * 16 + kn;
        const int n  = b * NPB + nl;
        const int startL = scanL[nl], d = cntL[nl];
        float s1a = 0.f, s2a = 0.f, s3a = 0.f, s4a = 0.f;   // feature c
        float s1b = 0.f, s2b = 0.f, s3b = 0.f, s4b = 0.f;   // feature c+16
        const int ntl = (d + 15) >> 4;

        for (int tl = 0; tl < ntl; tl++) {
            int row  = tl * 16 + c;
            int ridx = row < d ? row : d - 1;            // dup rows masked below (d>0 here)
            int li   = permL[startL + ridx];
            FU af;
            if (q < 2) {
                int tg = tgL[li];
                __builtin_memcpy(&af.v, x_tb + (size_t)tg * 16 + q * 8, 16);
            } else {
                __builtin_memcpy(&af.v, eaA + (size_t)(base + li) * 16 + (q - 2) * 8, 16);
            }

            f32x4 a0 = __builtin_amdgcn_mfma_f32_16x16x32_bf16(af.v, B1[0], zero, 0, 0, 0);
            f32x4 a1 = __builtin_amdgcn_mfma_f32_16x16x32_bf16(af.v, B1[1], zero, 0, 0, 0);
            #pragma unroll
            for (int r = 0; r < 4; r++) {
                h_lds[w][q * 4 + r][c]      = leaky(a0[r] + bias1[0], 0.1f);
                h_lds[w][q * 4 + r][c + 16] = leaky(a1[r] + bias1[1], 0.1f);
            }
            __asm__ volatile("s_waitcnt lgkmcnt(0)" ::: "memory");

            float hv[8];
            __builtin_memcpy(&hv, &h_lds[w][c][q * 8], 32);
            FU hf;
            #pragma unroll
            for (int j = 0; j < 8; j++) hf.s[j] = f2bf(hv[j]);
            f32x4 m0 = __builtin_amdgcn_mfma_f32_16x16x32_bf16(hf.v, B2[0], zero, 0, 0, 0);
            f32x4 m1 = __builtin_amdgcn_mfma_f32_16x16x32_bf16(hf.v, B2[1], zero, 0, 0, 0);

            int rb = tl * 16 + q * 4;
            #pragma unroll
            for (int r = 0; r < 4; r++) {
                if (rb + r < d) {
                    float m = m0[r] + bias2[0], mm = m * m;
                    s1a += m;  s2a += mm; s3a += mm * m; s4a += mm * mm;
                    float x = m1[r] + bias2[1], xx = x * x;
                    s1b += x;  s2b += xx; s3b += xx * x; s4b += xx * xx;
                }
            }
            // next tile's h_lds writes ordered after this tile's reads (per-wave in-order DS)
        }

        if (n >= N_NODES) continue;                     // tail bucket: nodes 50000..50047

        s1a += __shfl_xor(s1a, 16); s1a += __shfl_xor(s1a, 32);
        s2a += __shfl_xor(s2a, 16); s2a += __shfl_xor(s2a, 32);
        s3a += __shfl_xor(s3a, 16); s3a += __shfl_xor(s3a, 32);
        s4a += __shfl_xor(s4a, 16); s4a += __shfl_xor(s4a, 32);
        s1b += __shfl_xor(s1b, 16); s1b += __shfl_xor(s1b, 32);
        s2b += __shfl_xor(s2b, 16); s2b += __shfl_xor(s2b, 32);
        s3b += __shfl_xor(s3b, 16); s3b += __shfl_xor(s3b, 32);
        s4b += __shfl_xor(s4b, 16); s4b += __shfl_xor(s4b, 32);

        if (q == 0) {
            float denom = fmaxf((float)d, 1.f);
            {   // feature c
                float mean = s1a / denom, m2r = s2a / denom, m3r = s3a / denom, m4r = s4a / denom;
                float var  = leaky(m2r - mean * mean, 0.01f);
                float stdv = sqrtf(var + 1e-6f);
                float e3   = m3r - 3.f * mean * m2r + 2.f * mean * mean * mean;
                float skew = e3 / (stdv * stdv * stdv);
                float e4   = m4r - 4.f * mean * m3r + 6.f * mean * mean * m2r
                             - 3.f * mean * mean * mean * mean;
                float kurt = e4 / (stdv * stdv * stdv * stdv);
                stat_lds[w][c]      = f2bf(mean);
                stat_lds[w][32 + c] = f2bf(stdv);
                stat_lds[w][64 + c] = f2bf(skew);
                stat_lds[w][96 + c] = f2bf(kurt);
            }
            {   // feature c+16
                float mean = s1b / denom, m2r = s2b / denom, m3r = s3b / denom, m4r = s4b / denom;
                float var  = leaky(m2r - mean * mean, 0.01f);
                float stdv = sqrtf(var + 1e-6f);
                float e3   = m3r - 3.f * mean * m2r + 2.f * mean * mean * mean;
                float skew = e3 / (stdv * stdv * stdv);
                float e4   = m4r - 4.f * mean * m3r + 6.f * mean * mean * m2r
                             - 3.f * mean * mean * mean * mean;
                float kurt = e4 / (stdv * stdv * stdv * stdv);
                stat_lds[w][16 + c]  = f2bf(mean);
                stat_lds[w][48 + c]  = f2bf(stdv);
                stat_lds[w][80 + c]  = f2bf(skew);
                stat_lds[w][112 + c] = f2bf(kurt);
            }
        }
        __asm__ volatile("s_waitcnt lgkmcnt(0)" ::: "memory");

        const size_t basep = (size_t)n * 160;
        unsigned int sv;
        __builtin_memcpy(&sv, &stat_lds[w][L * 2], 4);
        *(unsigned int*)(hcat + basep + 16 + L * 2) = sv;   // coalesced 256 B stats store
        if (L < 16) {
            hcat[basep + L]       = f2bf(x_s[(size_t)n * 16 + L]);
            hcat[basep + 144 + L] = f2bf(u[L]);
        }
    }
}

// ---------------- K5: GEMM1 [N,160]@[160,160] + bias + leaky -> h2 (bf16) ----------------
__global__ __launch_bounds__(256) void k_gemm1(const ushort_t* __restrict__ hcat,
                                               const float* __restrict__ w1b,
                                               const float* __restrict__ b1b,
                                               ushort_t* __restrict__ h2)
{
    __shared__ __align__(16) ushort_t W1T[160 * 168];
    int t = threadIdx.x;
    for (int i = t; i < 160 * 160; i += 256) { int k = i / 160, n = i % 160; W1T[n * 168 + k] = f2bf(w1b[i]); }
    __syncthreads();
    int w = t >> 6, L = t & 63, q = L >> 4, c = L & 15;
    const f32x4 zero = { 0.f, 0.f, 0.f, 0.f };
    for (int tile = blockIdx.x * 4 + w; tile < 3125 * 10; tile += gridDim.x * 4) {
        int rt = tile / 10, nt = tile % 10;
        int m = rt * 16 + c, n = nt * 16 + c;
        f32x4 acc = zero;
        #pragma unroll
        for (int ks = 0; ks < 5; ks++) {
            bf16x8 a; __builtin_memcpy(&a, hcat + (size_t)m * 160 + ks * 32 + q * 8, 16);
            bf16x8 b; __builtin_memcpy(&b, &W1T[n * 168 + ks * 32 + q * 8], 16);
            acc = __builtin_amdgcn_mfma_f32_16x16x32_bf16(a, b, acc, 0, 0, 0);
        }
        float bias = b1b[n];
        #pragma unroll
        for (int r = 0; r < 4; r++) {
            h2[(size_t)(rt * 16 + q * 4 + r) * 160 + n] = f2bf(leaky(acc[r] + bias, 0.1f));
        }
    }
}

// ---------------- K6: GEMM2 [N,160]@[160,16] + bias -> outpre (fp32) + BN partials ----------
__global__ __launch_bounds__(256) void k_gemm2(const ushort_t* __restrict__ h2,
                                               const float* __restrict__ w2b,
                                               const float* __restrict__ b2b,
                                               float* __restrict__ outpre, float* __restrict__ bnsum)
{
    __shared__ __align__(16) ushort_t W2T[16 * 168];
    int t = threadIdx.x;
    for (int i = t; i < 160 * 16; i += 256) { int k = i / 16, n = i % 16; W2T[n * 168 + k] = f2bf(w2b[i]); }
    __syncthreads();
    int w = t >> 6, L = t & 63, q = L >> 4, c = L & 15;
    const f32x4 zero = { 0.f, 0.f, 0.f, 0.f };
    float ps = 0.f, ps2 = 0.f;
    float bias = b2b[c];
    for (int rt = blockIdx.x * 4 + w; rt < 3125; rt += gridDim.x * 4) {
        int m = rt * 16 + c;
        f32x4 acc = zero;
        #pragma unroll
        for (int ks = 0; ks < 5; ks++) {
            bf16x8 a; __builtin_memcpy(&a, h2 + (size_t)m * 160 + ks * 32 + q * 8, 16);
            bf16x8 b; __builtin_memcpy(&b, &W2T[c * 168 + ks * 32 + q * 8], 16);
            acc = __builtin_amdgcn_mfma_f32_16x16x32_bf16(a, b, acc, 0, 0, 0);
        }
        #pragma unroll
        for (int r = 0; r < 4; r++) {
            float v = acc[r] + bias;
            outpre[(size_t)(rt * 16 + q * 4 + r) * 16 + c] = v;
            ps += v; ps2 += v * v;
        }
    }
    ps  += __shfl_xor(ps, 16);  ps  += __shfl_xor(ps, 32);
    ps2 += __shfl_xor(ps2, 16); ps2 += __shfl_xor(ps2, 32);
    if (q == 0) {
        unsafeAtomicAdd(&bnsum[c], ps);
        unsafeAtomicAdd(&bnsum[16 + c], ps2);
    }
}

// ---------------- K7: BatchNorm apply -> d_out (fp32) ----------------
__global__ __launch_bounds__(256) void k_bn(const float* __restrict__ outpre, const float* __restrict__ bnsum,
                                            const float* __restrict__ gamma, const float* __restrict__ beta,
                                            float* __restrict__ out)
{
    int i = blockIdx.x * 256 + threadIdx.x;
    int c = i & 15;
    float x = outpre[i];
    float mu = bnsum[c] * (1.f / N_NODES);
    float var = bnsum[16 + c] * (1.f / N_NODES) - mu * mu;
    out[i] = gamma[c] * (x - mu) * rsqrtf(var + 1e-5f) + beta[c];
}

// ---------------- launch ----------------
extern "C" void kernel_launch(void* const* d_in, const int* in_sizes, int n_in,
                              void* d_out, int out_size, void* d_ws, size_t ws_size,
                              hipStream_t stream) {
    const float* x_s  = (const float*)d_in[0];
    const float* x_t  = (const float*)d_in[1];
    const float* ea   = (const float*)d_in[2];
    const float* u    = (const float*)d_in[3];
    const float* w1a  = (const float*)d_in[4];
    const float* b1a  = (const float*)d_in[5];
    const float* w2a  = (const float*)d_in[6];
    const float* b2a  = (const float*)d_in[7];
    const float* w1b  = (const float*)d_in[8];
    const float* b1b  = (const float*)d_in[9];
    const float* w2b  = (const float*)d_in[10];
    const float* b2b  = (const float*)d_in[11];
    const float* gam  = (const float*)d_in[12];
    const float* bet  = (const float*)d_in[13];
    const int* eidx   = (const int*)d_in[14];
    const int* src = eidx;
    const int* tgt = eidx + N_EDGES;

    char* ws = (char*)d_ws;
    // workspace layout (bytes) — ws_size >= 138,001,536 proven; peak used ~101 MB.
    //   table  [0         ,   613,088)  int[153272]; k_bcount -> k_bscan -> k_bscat/k_nodeF
    //   bnsum  [  655,360 ,   655,488)  float[32]; zeroed in k_bscan
    //   outpre [  786,432 , 3,986,432)  float[800000]
    //   x_tb   [4,194,304 , 5,794,304)  bf16[50000*16]; k_cvtx -> k_nodeF
    //   tnA    [6,291,456 ,12,691,456)  int[1.6M] (tgt | node_local<<16); k_bscat -> k_nodeF
    //   eaA    [16,777,216,67,977,216)  bf16[1.6M*16]; k_bscat -> k_nodeF
    //   hcat   [68,157,440,84,157,440)  bf16[50000*160]; k_nodeF -> k_gemm1
    //   h2     [84,934,656,100,934,656) bf16[50000*160]; k_gemm1 -> k_gemm2
    const size_t OFF_TABLE  = 0;
    const size_t OFF_BNSUM  = 655360;
    const size_t OFF_OUTPRE = 786432;
    const size_t OFF_XTB    = 4194304;
    const size_t OFF_TNA    = 6291456;
    const size_t OFF_EAA    = 16777216;
    const size_t OFF_HCAT   = 68157440;
    const size_t OFF_H2     = 84934656;

    int*      table  = (int*)(ws + OFF_TABLE);
    float*    bnsum  = (float*)(ws + OFF_BNSUM);
    float*    outpre = (float*)(ws + OFF_OUTPRE);
    ushort_t* x_tb   = (ushort_t*)(ws + OFF_XTB);
    int*      tnA    = (int*)(ws + OFF_TNA);
    ushort_t* eaA    = (ushort_t*)(ws + OFF_EAA);
    ushort_t* hcat   = (ushort_t*)(ws + OFF_HCAT);
    ushort_t* h2     = (ushort_t*)(ws + OFF_H2);

    k_cvtx  <<<(N_NODES * 16 / 4 + 255) / 256, 256, 0, stream>>>(x_t, x_tb);
    k_bcount<<<NB1, 256, 0, stream>>>(src, table);
    k_bscan <<<1,   256, 0, stream>>>(table, bnsum);
    k_bscat <<<NB1, 256, 0, stream>>>(src, tgt, ea, table, tnA, eaA);
    k_nodeF <<<NBK, 256, 0, stream>>>(x_tb, eaA, tnA, table, w1a, b1a, w2a, b2a, x_s, u, hcat);
    k_gemm1 <<<1024, 256, 0, stream>>>(hcat, w1b, b1b, h2);
    k_gemm2 <<<512,  256, 0, stream>>>(h2, w2b, b2b, outpre, bnsum);
    k_bn    <<<(N_NODES * 16) / 256, 256, 0, stream>>>(outpre, bnsum, gam, bet, (float*)d_out);
}

// Round 6
// 451.931 us; speedup vs baseline: 4.3171x; 1.5414x over previous
//
#include <hip/hip_runtime.h>

#define N_NODES 50000
#define N_EDGES 1600000

// bucket geometry
#define EPB 8192                          // edges per chunk-block
#define NB1 ((N_EDGES + EPB - 1) / EPB)   // 196 chunks
#define NPB 64                            // nodes per bucket
#define NBK ((N_NODES + NPB - 1) / NPB)   // 782 buckets
#define TBL (NBK * NB1)                   // 153272 table entries
#define NSB ((TBL + 255) / 256)           // 599 scan blocks
#define MAXB 4096                         // LDS capacity per bucket (mean 2048, sigma ~45)

typedef unsigned short ushort_t;
typedef __attribute__((ext_vector_type(8))) __bf16 bf16x8;
typedef __attribute__((ext_vector_type(4))) float  f32x4;

union FU { ushort_t s[8]; bf16x8 v; };

__device__ __forceinline__ ushort_t f2bf(float f) {
    union { float f; unsigned int i; } v; v.f = f;
    unsigned int r = v.i + 0x7fffu + ((v.i >> 16) & 1u);
    return (ushort_t)(r >> 16);
}
__device__ __forceinline__ float leaky(float x, float s) { return x >= 0.f ? x : s * x; }

// ---------------- K0: x_t -> bf16 (1.6 MB, L2-resident gather target) ----------------
__global__ __launch_bounds__(256) void k_cvtx(const float* __restrict__ x_t,
                                              ushort_t* __restrict__ x_tb) {
    int i = blockIdx.x * 256 + threadIdx.x;          // one f32x4 (4 elems) per thread
    if (i < (N_NODES * 16) / 4) {
        f32x4 v = ((const f32x4*)x_t)[i];
        unsigned long long p = (unsigned long long)f2bf(v[0])
                             | ((unsigned long long)f2bf(v[1]) << 16)
                             | ((unsigned long long)f2bf(v[2]) << 32)
                             | ((unsigned long long)f2bf(v[3]) << 48);
        ((unsigned long long*)x_tb)[i] = p;
    }
}

// ---------------- K1: per-(bucket, chunk) histogram (LDS int atomics only) ----------------
__global__ __launch_bounds__(256) void k_bcount(const int* __restrict__ src, int* __restrict__ table) {
    __shared__ int cnt[NBK];
    const int t = threadIdx.x, blk = blockIdx.x;
    for (int i = t; i < NBK; i += 256) cnt[i] = 0;
    __syncthreads();
    const int base = blk * EPB;
    for (int i = t; i < EPB; i += 256) {
        int e = base + i;
        if (e < N_EDGES) atomicAdd(&cnt[src[e] >> 6], 1);   // NPB = 64
    }
    __syncthreads();
    for (int b = t; b < NBK; b += 256) table[b * NB1 + blk] = cnt[b];
}

// ---------------- K2a/b/c: hierarchical exclusive scan of the 153 K-entry table ------------
// Replaces the single-block scan (258 us, 1 CU, latency-bound) with 3 trivial kernels.
__global__ __launch_bounds__(256) void k_scan1(int* __restrict__ table, int* __restrict__ bsum) {
    __shared__ int buf[256];
    const int t = threadIdx.x, i = blockIdx.x * 256 + t;
    int v = (i < TBL) ? table[i] : 0;
    buf[t] = v; __syncthreads();
    for (int off = 1; off < 256; off <<= 1) {
        int x = (t >= off) ? buf[t - off] : 0;
        __syncthreads(); buf[t] += x; __syncthreads();
    }
    int incl = buf[t];
    if (i < TBL) table[i] = incl - v;                    // block-local exclusive
    if (t == 255) bsum[blockIdx.x] = incl;
}
__global__ __launch_bounds__(256) void k_scan2(int* __restrict__ bsum, float* __restrict__ bnsum) {
    __shared__ int sums[256];
    const int t = threadIdx.x;
    if (t < 32) bnsum[t] = 0.f;
    const int SEG = (NSB + 255) / 256;                   // 3
    const int s0 = t * SEG, s1 = (s0 + SEG < NSB) ? s0 + SEG : NSB;
    int sum = 0;
    for (int i = s0; i < s1; i++) sum += bsum[i];
    sums[t] = sum; __syncthreads();
    for (int off = 1; off < 256; off <<= 1) {
        int x = (t >= off) ? sums[t - off] : 0;
        __syncthreads(); sums[t] += x; __syncthreads();
    }
    int carry = sums[t] - sum;
    for (int i = s0; i < s1; i++) { int v = bsum[i]; bsum[i] = carry; carry += v; }
}
__global__ __launch_bounds__(256) void k_scan3(int* __restrict__ table, const int* __restrict__ bsum) {
    const int i = blockIdx.x * 256 + threadIdx.x;
    if (i < TBL) table[i] += bsum[blockIdx.x];
}

// ---------------- K3: edge-order record deposit (proven) ----------------
// Sequential src/tgt/ea reads; record = [tgt | node_local<<16] (4 B) + ea bf16 (32 B)
// written into per-(bucket,chunk) runs -> L2 write-combined full lines.
__global__ __launch_bounds__(256) void k_bscat(const int* __restrict__ src, const int* __restrict__ tgt,
                                               const float* __restrict__ ea, const int* __restrict__ table,
                                               int* __restrict__ tnA, ushort_t* __restrict__ eaA) {
    __shared__ int cur[NBK];
    const int t = threadIdx.x, blk = blockIdx.x;
    for (int i = t; i < NBK; i += 256) cur[i] = table[i * NB1 + blk];
    __syncthreads();
    const int base = blk * EPB;
    for (int i = t; i < EPB; i += 256) {
        int e = base + i;
        if (e < N_EDGES) {
            int s = src[e];
            int pos = atomicAdd(&cur[s >> 6], 1);            // LDS int atomic (native)
            tnA[pos] = tgt[e] | ((s & (NPB - 1)) << 16);     // tgt < 2^16
            const f32x4* ep = (const f32x4*)(ea + (size_t)e * 16);
            f32x4 v0 = __builtin_nontemporal_load(ep);
            f32x4 v1 = __builtin_nontemporal_load(ep + 1);
            f32x4 v2 = __builtin_nontemporal_load(ep + 2);
            f32x4 v3 = __builtin_nontemporal_load(ep + 3);
            FU lo, hi;
            #pragma unroll
            for (int j = 0; j < 4; j++) {
                lo.s[j] = f2bf(v0[j]); lo.s[4 + j] = f2bf(v1[j]);
                hi.s[j] = f2bf(v2[j]); hi.s[4 + j] = f2bf(v3[j]);
            }
            *(bf16x8*)(eaA + (size_t)pos * 16)     = lo.v;
            *(bf16x8*)(eaA + (size_t)pos * 16 + 8) = hi.v;
        }
    }
}

// ---------------- K4: per-bucket node-sort prologue + wave-per-node register moments --------
// (unchanged from round 5 — proven correct; LDS INT atomics only, register power sums)
__global__ __launch_bounds__(256) void k_nodeF(
    const ushort_t* __restrict__ x_tb, const ushort_t* __restrict__ eaA, const int* __restrict__ tnA,
    const int* __restrict__ table,
    const float* __restrict__ w1a, const float* __restrict__ b1a,
    const float* __restrict__ w2a, const float* __restrict__ b2a,
    const float* __restrict__ x_s, const float* __restrict__ u,
    ushort_t* __restrict__ hcat)
{
    __shared__ ushort_t permL[MAXB];                    // node-sorted local indices
    __shared__ ushort_t tgL[MAXB];                      // tgt per local index
    __shared__ int cntL[NPB], scanL[NPB], curL[NPB];
    __shared__ __align__(16) float h_lds[4][16][36];    // wave-private h slice (proven)
    __shared__ ushort_t stat_lds[4][128];               // wave-private stats staging

    const int t = threadIdx.x;
    const int w = t >> 6, L = t & 63, q = L >> 4, c = L & 15;
    const int b = blockIdx.x;
    const int base  = table[b * NB1];
    const int end   = (b < NBK - 1) ? table[(b + 1) * NB1] : N_EDGES;
    const int cntB0 = end - base;
    const int cntB  = cntB0 < MAXB ? cntB0 : MAXB;      // safety clamp (never hit: +45 sigma)

    if (t < NPB) cntL[t] = 0;
    __syncthreads();
    for (int i = t; i < cntB; i += 256) {
        int v = tnA[base + i];
        tgL[i] = (ushort_t)(v & 0xFFFF);
        atomicAdd(&cntL[v >> 16], 1);                   // LDS int atomic
    }
    __syncthreads();
    if (t == 0) {
        int s = 0;
        for (int nl = 0; nl < NPB; nl++) { scanL[nl] = s; s += cntL[nl]; }
    }
    __syncthreads();
    if (t < NPB) curL[t] = scanL[t];
    __syncthreads();
    for (int i = t; i < cntB; i += 256) {
        int nl = tnA[base + i] >> 16;
        int loc = atomicAdd(&curL[nl], 1);              // LDS int atomic
        permL[loc] = (ushort_t)i;
    }

    // weight fragments (B-operand layout: col = c+16h, k = q*8+j) — proven layout
    bf16x8 B1[2], B2[2];
    #pragma unroll
    for (int h = 0; h < 2; h++) {
        FU u1, u2;
        #pragma unroll
        for (int j = 0; j < 8; j++) {
            int kk = q * 8 + j, nn = c + 16 * h;
            u1.s[j] = f2bf(w1a[kk * 32 + nn]);
            u2.s[j] = f2bf(w2a[kk * 32 + nn]);
        }
        B1[h] = u1.v; B2[h] = u2.v;
    }
    const float bias1[2] = { b1a[c], b1a[c + 16] };
    const float bias2[2] = { b2a[c], b2a[c + 16] };
    const f32x4 zero = { 0.f, 0.f, 0.f, 0.f };
    __syncthreads();                                    // perm/tgL visible to all waves

    for (int kn = 0; kn < 16; kn++) {
        const int nl = w * 16 + kn;
        const int n  = b * NPB + nl;
        const int startL = scanL[nl], d = cntL[nl];
        float s1a = 0.f, s2a = 0.f, s3a = 0.f, s4a = 0.f;   // feature c
        float s1b = 0.f, s2b = 0.f, s3b = 0.f, s4b = 0.f;   // feature c+16
        const int ntl = (d + 15) >> 4;

        for (int tl = 0; tl < ntl; tl++) {
            int row  = tl * 16 + c;
            int ridx = row < d ? row : d - 1;            // dup rows masked below (d>0 here)
            int li   = permL[startL + ridx];
            FU af;
            if (q < 2) {
                int tg = tgL[li];
                __builtin_memcpy(&af.v, x_tb + (size_t)tg * 16 + q * 8, 16);
            } else {
                __builtin_memcpy(&af.v, eaA + (size_t)(base + li) * 16 + (q - 2) * 8, 16);
            }

            f32x4 a0 = __builtin_amdgcn_mfma_f32_16x16x32_bf16(af.v, B1[0], zero, 0, 0, 0);
            f32x4 a1 = __builtin_amdgcn_mfma_f32_16x16x32_bf16(af.v, B1[1], zero, 0, 0, 0);
            #pragma unroll
            for (int r = 0; r < 4; r++) {
                h_lds[w][q * 4 + r][c]      = leaky(a0[r] + bias1[0], 0.1f);
                h_lds[w][q * 4 + r][c + 16] = leaky(a1[r] + bias1[1], 0.1f);
            }
            __asm__ volatile("s_waitcnt lgkmcnt(0)" ::: "memory");

            float hv[8];
            __builtin_memcpy(&hv, &h_lds[w][c][q * 8], 32);
            FU hf;
            #pragma unroll
            for (int j = 0; j < 8; j++) hf.s[j] = f2bf(hv[j]);
            f32x4 m0 = __builtin_amdgcn_mfma_f32_16x16x32_bf16(hf.v, B2[0], zero, 0, 0, 0);
            f32x4 m1 = __builtin_amdgcn_mfma_f32_16x16x32_bf16(hf.v, B2[1], zero, 0, 0, 0);

            int rb = tl * 16 + q * 4;
            #pragma unroll
            for (int r = 0; r < 4; r++) {
                if (rb + r < d) {
                    float m = m0[r] + bias2[0], mm = m * m;
                    s1a += m;  s2a += mm; s3a += mm * m; s4a += mm * mm;
                    float x = m1[r] + bias2[1], xx = x * x;
                    s1b += x;  s2b += xx; s3b += xx * x; s4b += xx * xx;
                }
            }
            // next tile's h_lds writes ordered after this tile's reads (per-wave in-order DS)
        }

        if (n >= N_NODES) continue;                     // tail bucket: nodes 50000..50047

        s1a += __shfl_xor(s1a, 16); s1a += __shfl_xor(s1a, 32);
        s2a += __shfl_xor(s2a, 16); s2a += __shfl_xor(s2a, 32);
        s3a += __shfl_xor(s3a, 16); s3a += __shfl_xor(s3a, 32);
        s4a += __shfl_xor(s4a, 16); s4a += __shfl_xor(s4a, 32);
        s1b += __shfl_xor(s1b, 16); s1b += __shfl_xor(s1b, 32);
        s2b += __shfl_xor(s2b, 16); s2b += __shfl_xor(s2b, 32);
        s3b += __shfl_xor(s3b, 16); s3b += __shfl_xor(s3b, 32);
        s4b += __shfl_xor(s4b, 16); s4b += __shfl_xor(s4b, 32);

        if (q == 0) {
            float denom = fmaxf((float)d, 1.f);
            {   // feature c
                float mean = s1a / denom, m2r = s2a / denom, m3r = s3a / denom, m4r = s4a / denom;
                float var  = leaky(m2r - mean * mean, 0.01f);
                float stdv = sqrtf(var + 1e-6f);
                float e3   = m3r - 3.f * mean * m2r + 2.f * mean * mean * mean;
                float skew = e3 / (stdv * stdv * stdv);
                float e4   = m4r - 4.f * mean * m3r + 6.f * mean * mean * m2r
                             - 3.f * mean * mean * mean * mean;
                float kurt = e4 / (stdv * stdv * stdv * stdv);
                stat_lds[w][c]      = f2bf(mean);
                stat_lds[w][32 + c] = f2bf(stdv);
                stat_lds[w][64 + c] = f2bf(skew);
                stat_lds[w][96 + c] = f2bf(kurt);
            }
            {   // feature c+16
                float mean = s1b / denom, m2r = s2b / denom, m3r = s3b / denom, m4r = s4b / denom;
                float var  = leaky(m2r - mean * mean, 0.01f);
                float stdv = sqrtf(var + 1e-6f);
                float e3   = m3r - 3.f * mean * m2r + 2.f * mean * mean * mean;
                float skew = e3 / (stdv * stdv * stdv);
                float e4   = m4r - 4.f * mean * m3r + 6.f * mean * mean * m2r
                             - 3.f * mean * mean * mean * mean;
                float kurt = e4 / (stdv * stdv * stdv * stdv);
                stat_lds[w][16 + c]  = f2bf(mean);
                stat_lds[w][48 + c]  = f2bf(stdv);
                stat_lds[w][80 + c]  = f2bf(skew);
                stat_lds[w][112 + c] = f2bf(kurt);
            }
        }
        __asm__ volatile("s_waitcnt lgkmcnt(0)" ::: "memory");

        const size_t basep = (size_t)n * 160;
        unsigned int sv;
        __builtin_memcpy(&sv, &stat_lds[w][L * 2], 4);
        *(unsigned int*)(hcat + basep + 16 + L * 2) = sv;   // coalesced 256 B stats store
        if (L < 16) {
            hcat[basep + L]       = f2bf(x_s[(size_t)n * 16 + L]);
            hcat[basep + 144 + L] = f2bf(u[L]);
        }
    }
}

// ---------------- K5: GEMM1 [N,160]@[160,160] + bias + leaky -> h2 (bf16) ----------------
__global__ __launch_bounds__(256) void k_gemm1(const ushort_t* __restrict__ hcat,
                                               const float* __restrict__ w1b,
                                               const float* __restrict__ b1b,
                                               ushort_t* __restrict__ h2)
{
    __shared__ __align__(16) ushort_t W1T[160 * 168];
    int t = threadIdx.x;
    for (int i = t; i < 160 * 160; i += 256) { int k = i / 160, n = i % 160; W1T[n * 168 + k] = f2bf(w1b[i]); }
    __syncthreads();
    int w = t >> 6, L = t & 63, q = L >> 4, c = L & 15;
    const f32x4 zero = { 0.f, 0.f, 0.f, 0.f };
    for (int tile = blockIdx.x * 4 + w; tile < 3125 * 10; tile += gridDim.x * 4) {
        int rt = tile / 10, nt = tile % 10;
        int m = rt * 16 + c, n = nt * 16 + c;
        f32x4 acc = zero;
        #pragma unroll
        for (int ks = 0; ks < 5; ks++) {
            bf16x8 a; __builtin_memcpy(&a, hcat + (size_t)m * 160 + ks * 32 + q * 8, 16);
            bf16x8 b; __builtin_memcpy(&b, &W1T[n * 168 + ks * 32 + q * 8], 16);
            acc = __builtin_amdgcn_mfma_f32_16x16x32_bf16(a, b, acc, 0, 0, 0);
        }
        float bias = b1b[n];
        #pragma unroll
        for (int r = 0; r < 4; r++) {
            h2[(size_t)(rt * 16 + q * 4 + r) * 160 + n] = f2bf(leaky(acc[r] + bias, 0.1f));
        }
    }
}

// ---------------- K6: GEMM2 [N,160]@[160,16] + bias -> outpre (fp32) + BN partials ----------
__global__ __launch_bounds__(256) void k_gemm2(const ushort_t* __restrict__ h2,
                                               const float* __restrict__ w2b,
                                               const float* __restrict__ b2b,
                                               float* __restrict__ outpre, float* __restrict__ bnsum)
{
    __shared__ __align__(16) ushort_t W2T[16 * 168];
    int t = threadIdx.x;
    for (int i = t; i < 160 * 16; i += 256) { int k = i / 16, n = i % 16; W2T[n * 168 + k] = f2bf(w2b[i]); }
    __syncthreads();
    int w = t >> 6, L = t & 63, q = L >> 4, c = L & 15;
    const f32x4 zero = { 0.f, 0.f, 0.f, 0.f };
    float ps = 0.f, ps2 = 0.f;
    float bias = b2b[c];
    for (int rt = blockIdx.x * 4 + w; rt < 3125; rt += gridDim.x * 4) {
        int m = rt * 16 + c;
        f32x4 acc = zero;
        #pragma unroll
        for (int ks = 0; ks < 5; ks++) {
            bf16x8 a; __builtin_memcpy(&a, h2 + (size_t)m * 160 + ks * 32 + q * 8, 16);
            bf16x8 b; __builtin_memcpy(&b, &W2T[c * 168 + ks * 32 + q * 8], 16);
            acc = __builtin_amdgcn_mfma_f32_16x16x32_bf16(a, b, acc, 0, 0, 0);
        }
        #pragma unroll
        for (int r = 0; r < 4; r++) {
            float v = acc[r] + bias;
            outpre[(size_t)(rt * 16 + q * 4 + r) * 16 + c] = v;
            ps += v; ps2 += v * v;
        }
    }
    ps  += __shfl_xor(ps, 16);  ps  += __shfl_xor(ps, 32);
    ps2 += __shfl_xor(ps2, 16); ps2 += __shfl_xor(ps2, 32);
    if (q == 0) {
        unsafeAtomicAdd(&bnsum[c], ps);
        unsafeAtomicAdd(&bnsum[16 + c], ps2);
    }
}

// ---------------- K7: BatchNorm apply -> d_out (fp32) ----------------
__global__ __launch_bounds__(256) void k_bn(const float* __restrict__ outpre, const float* __restrict__ bnsum,
                                            const float* __restrict__ gamma, const float* __restrict__ beta,
                                            float* __restrict__ out)
{
    int i = blockIdx.x * 256 + threadIdx.x;
    int c = i & 15;
    float x = outpre[i];
    float mu = bnsum[c] * (1.f / N_NODES);
    float var = bnsum[16 + c] * (1.f / N_NODES) - mu * mu;
    out[i] = gamma[c] * (x - mu) * rsqrtf(var + 1e-5f) + beta[c];
}

// ---------------- launch ----------------
extern "C" void kernel_launch(void* const* d_in, const int* in_sizes, int n_in,
                              void* d_out, int out_size, void* d_ws, size_t ws_size,
                              hipStream_t stream) {
    const float* x_s  = (const float*)d_in[0];
    const float* x_t  = (const float*)d_in[1];
    const float* ea   = (const float*)d_in[2];
    const float* u    = (const float*)d_in[3];
    const float* w1a  = (const float*)d_in[4];
    const float* b1a  = (const float*)d_in[5];
    const float* w2a  = (const float*)d_in[6];
    const float* b2a  = (const float*)d_in[7];
    const float* w1b  = (const float*)d_in[8];
    const float* b1b  = (const float*)d_in[9];
    const float* w2b  = (const float*)d_in[10];
    const float* b2b  = (const float*)d_in[11];
    const float* gam  = (const float*)d_in[12];
    const float* bet  = (const float*)d_in[13];
    const int* eidx   = (const int*)d_in[14];
    const int* src = eidx;
    const int* tgt = eidx + N_EDGES;

    char* ws = (char*)d_ws;
    // workspace layout (bytes) — ws_size >= 138,001,536 proven; peak used ~101 MB.
    //   table  [0         ,   613,088)  int[153272]; k_bcount -> scan trio -> k_bscat/k_nodeF
    //   bsum   [  614,400 ,   616,796)  int[599]; scan trio scratch
    //   bnsum  [  655,360 ,   655,488)  float[32]; zeroed in k_scan2
    //   outpre [  786,432 , 3,986,432)  float[800000]
    //   x_tb   [4,194,304 , 5,794,304)  bf16[50000*16]; k_cvtx -> k_nodeF
    //   tnA    [6,291,456 ,12,691,456)  int[1.6M] (tgt | node_local<<16); k_bscat -> k_nodeF
    //   eaA    [16,777,216,67,977,216)  bf16[1.6M*16]; k_bscat -> k_nodeF
    //   hcat   [68,157,440,84,157,440)  bf16[50000*160]; k_nodeF -> k_gemm1
    //   h2     [84,934,656,100,934,656) bf16[50000*160]; k_gemm1 -> k_gemm2
    const size_t OFF_TABLE  = 0;
    const size_t OFF_BSUM   = 614400;
    const size_t OFF_BNSUM  = 655360;
    const size_t OFF_OUTPRE = 786432;
    const size_t OFF_XTB    = 4194304;
    const size_t OFF_TNA    = 6291456;
    const size_t OFF_EAA    = 16777216;
    const size_t OFF_HCAT   = 68157440;
    const size_t OFF_H2     = 84934656;

    int*      table  = (int*)(ws + OFF_TABLE);
    int*      bsum   = (int*)(ws + OFF_BSUM);
    float*    bnsum  = (float*)(ws + OFF_BNSUM);
    float*    outpre = (float*)(ws + OFF_OUTPRE);
    ushort_t* x_tb   = (ushort_t*)(ws + OFF_XTB);
    int*      tnA    = (int*)(ws + OFF_TNA);
    ushort_t* eaA    = (ushort_t*)(ws + OFF_EAA);
    ushort_t* hcat   = (ushort_t*)(ws + OFF_HCAT);
    ushort_t* h2     = (ushort_t*)(ws + OFF_H2);

    k_cvtx  <<<(N_NODES * 16 / 4 + 255) / 256, 256, 0, stream>>>(x_t, x_tb);
    k_bcount<<<NB1, 256, 0, stream>>>(src, table);
    k_scan1 <<<NSB, 256, 0, stream>>>(table, bsum);
    k_scan2 <<<1,   256, 0, stream>>>(bsum, bnsum);
    k_scan3 <<<NSB, 256, 0, stream>>>(table, bsum);
    k_bscat <<<NB1, 256, 0, stream>>>(src, tgt, ea, table, tnA, eaA);
    k_nodeF <<<NBK, 256, 0, stream>>>(x_tb, eaA, tnA, table, w1a, b1a, w2a, b2a, x_s, u, hcat);
    k_gemm1 <<<1024, 256, 0, stream>>>(hcat, w1b, b1b, h2);
    k_gemm2 <<<512,  256, 0, stream>>>(h2, w2b, b2b, outpre, bnsum);
    k_bn    <<<(N_NODES * 16) / 256, 256, 0, stream>>>(outpre, bnsum, gam, bet, (float*)d_out);
}

// Round 7
// 429.930 us; speedup vs baseline: 4.5380x; 1.0512x over previous
//
#include <hip/hip_runtime.h>

#define N_NODES 50000
#define N_EDGES 1600000

// bucket geometry
#define EPB 8192                          // edges per chunk-block
#define NB1 ((N_EDGES + EPB - 1) / EPB)   // 196 chunks
#define NPB 64                            // nodes per bucket
#define NBK ((N_NODES + NPB - 1) / NPB)   // 782 buckets
#define TBL (NBK * NB1)                   // 153272 table entries
#define NSB ((TBL + 255) / 256)           // 599 scan blocks
#define MAXB 4096                         // LDS capacity per bucket (mean 2048, sigma ~45)
#define SCATB 1024                        // k_bcount/k_bscat block size (16 waves: latency hiding)

typedef unsigned short ushort_t;
typedef __attribute__((ext_vector_type(8))) __bf16 bf16x8;
typedef __attribute__((ext_vector_type(4))) float  f32x4;

union FU { ushort_t s[8]; bf16x8 v; };

__device__ __forceinline__ ushort_t f2bf(float f) {
    union { float f; unsigned int i; } v; v.f = f;
    unsigned int r = v.i + 0x7fffu + ((v.i >> 16) & 1u);
    return (ushort_t)(r >> 16);
}
__device__ __forceinline__ float leaky(float x, float s) { return x >= 0.f ? x : s * x; }

// ---------------- K0: x_t -> bf16 (1.6 MB, L2-resident gather target) ----------------
__global__ __launch_bounds__(256) void k_cvtx(const float* __restrict__ x_t,
                                              ushort_t* __restrict__ x_tb) {
    int i = blockIdx.x * 256 + threadIdx.x;          // one f32x4 (4 elems) per thread
    if (i < (N_NODES * 16) / 4) {
        f32x4 v = ((const f32x4*)x_t)[i];
        unsigned long long p = (unsigned long long)f2bf(v[0])
                             | ((unsigned long long)f2bf(v[1]) << 16)
                             | ((unsigned long long)f2bf(v[2]) << 32)
                             | ((unsigned long long)f2bf(v[3]) << 48);
        ((unsigned long long*)x_tb)[i] = p;
    }
}

// ---------------- K1: per-(bucket, chunk) histogram (LDS int atomics only) ----------------
// 1024-thread blocks: 196 blocks x 16 waves -> enough waves to hide gather latency.
__global__ __launch_bounds__(SCATB) void k_bcount(const int* __restrict__ src, int* __restrict__ table) {
    __shared__ int cnt[NBK];
    const int t = threadIdx.x, blk = blockIdx.x;
    for (int i = t; i < NBK; i += SCATB) cnt[i] = 0;
    __syncthreads();
    const int base = blk * EPB;
    for (int i = t; i < EPB; i += SCATB) {
        int e = base + i;
        if (e < N_EDGES) atomicAdd(&cnt[src[e] >> 6], 1);   // NPB = 64
    }
    __syncthreads();
    for (int b = t; b < NBK; b += SCATB) table[b * NB1 + blk] = cnt[b];
}

// ---------------- K2a/b/c: hierarchical exclusive scan of the 153 K-entry table ------------
__global__ __launch_bounds__(256) void k_scan1(int* __restrict__ table, int* __restrict__ bsum) {
    __shared__ int buf[256];
    const int t = threadIdx.x, i = blockIdx.x * 256 + t;
    int v = (i < TBL) ? table[i] : 0;
    buf[t] = v; __syncthreads();
    for (int off = 1; off < 256; off <<= 1) {
        int x = (t >= off) ? buf[t - off] : 0;
        __syncthreads(); buf[t] += x; __syncthreads();
    }
    int incl = buf[t];
    if (i < TBL) table[i] = incl - v;                    // block-local exclusive
    if (t == 255) bsum[blockIdx.x] = incl;
}
__global__ __launch_bounds__(256) void k_scan2(int* __restrict__ bsum, float* __restrict__ bnsum) {
    __shared__ int sums[256];
    const int t = threadIdx.x;
    if (t < 32) bnsum[t] = 0.f;
    const int SEG = (NSB + 255) / 256;                   // 3
    const int s0 = t * SEG, s1 = (s0 + SEG < NSB) ? s0 + SEG : NSB;
    int sum = 0;
    for (int i = s0; i < s1; i++) sum += bsum[i];
    sums[t] = sum; __syncthreads();
    for (int off = 1; off < 256; off <<= 1) {
        int x = (t >= off) ? sums[t - off] : 0;
        __syncthreads(); sums[t] += x; __syncthreads();
    }
    int carry = sums[t] - sum;
    for (int i = s0; i < s1; i++) { int v = bsum[i]; bsum[i] = carry; carry += v; }
}
__global__ __launch_bounds__(256) void k_scan3(int* __restrict__ table, const int* __restrict__ bsum) {
    const int i = blockIdx.x * 256 + threadIdx.x;
    if (i < TBL) table[i] += bsum[blockIdx.x];
}

// ---------------- K3: edge-order record deposit ----------------
// 1024-thread blocks (was 256: OccupancyPercent 7.8% -> latency-bound at 1.4 TB/s).
// Sequential src/tgt/ea reads; record = [tgt | node_local<<16] (4 B) + ea bf16 (32 B)
// written into per-(bucket,chunk) runs -> L2 write-combined full lines.
__global__ __launch_bounds__(SCATB) void k_bscat(const int* __restrict__ src, const int* __restrict__ tgt,
                                                 const float* __restrict__ ea, const int* __restrict__ table,
                                                 int* __restrict__ tnA, ushort_t* __restrict__ eaA) {
    __shared__ int cur[NBK];
    const int t = threadIdx.x, blk = blockIdx.x;
    for (int i = t; i < NBK; i += SCATB) cur[i] = table[i * NB1 + blk];
    __syncthreads();
    const int base = blk * EPB;
    for (int i = t; i < EPB; i += SCATB) {
        int e = base + i;
        if (e < N_EDGES) {
            int s = src[e];
            int pos = atomicAdd(&cur[s >> 6], 1);            // LDS int atomic (native)
            tnA[pos] = tgt[e] | ((s & (NPB - 1)) << 16);     // tgt < 2^16
            const f32x4* ep = (const f32x4*)(ea + (size_t)e * 16);
            f32x4 v0 = __builtin_nontemporal_load(ep);
            f32x4 v1 = __builtin_nontemporal_load(ep + 1);
            f32x4 v2 = __builtin_nontemporal_load(ep + 2);
            f32x4 v3 = __builtin_nontemporal_load(ep + 3);
            FU lo, hi;
            #pragma unroll
            for (int j = 0; j < 4; j++) {
                lo.s[j] = f2bf(v0[j]); lo.s[4 + j] = f2bf(v1[j]);
                hi.s[j] = f2bf(v2[j]); hi.s[4 + j] = f2bf(v3[j]);
            }
            *(bf16x8*)(eaA + (size_t)pos * 16)     = lo.v;
            *(bf16x8*)(eaA + (size_t)pos * 16 + 8) = hi.v;
        }
    }
}

// ---------------- K4: per-bucket node-sort prologue + wave-per-node register moments --------
// (unchanged — proven correct; LDS INT atomics only, register power sums)
__global__ __launch_bounds__(256) void k_nodeF(
    const ushort_t* __restrict__ x_tb, const ushort_t* __restrict__ eaA, const int* __restrict__ tnA,
    const int* __restrict__ table,
    const float* __restrict__ w1a, const float* __restrict__ b1a,
    const float* __restrict__ w2a, const float* __restrict__ b2a,
    const float* __restrict__ x_s, const float* __restrict__ u,
    ushort_t* __restrict__ hcat)
{
    __shared__ ushort_t permL[MAXB];                    // node-sorted local indices
    __shared__ ushort_t tgL[MAXB];                      // tgt per local index
    __shared__ int cntL[NPB], scanL[NPB], curL[NPB];
    __shared__ __align__(16) float h_lds[4][16][36];    // wave-private h slice (proven)
    __shared__ ushort_t stat_lds[4][128];               // wave-private stats staging

    const int t = threadIdx.x;
    const int w = t >> 6, L = t & 63, q = L >> 4, c = L & 15;
    const int b = blockIdx.x;
    const int base  = table[b * NB1];
    const int end   = (b < NBK - 1) ? table[(b + 1) * NB1] : N_EDGES;
    const int cntB0 = end - base;
    const int cntB  = cntB0 < MAXB ? cntB0 : MAXB;      // safety clamp (never hit: +45 sigma)

    if (t < NPB) cntL[t] = 0;
    __syncthreads();
    for (int i = t; i < cntB; i += 256) {
        int v = tnA[base + i];
        tgL[i] = (ushort_t)(v & 0xFFFF);
        atomicAdd(&cntL[v >> 16], 1);                   // LDS int atomic
    }
    __syncthreads();
    if (t == 0) {
        int s = 0;
        for (int nl = 0; nl < NPB; nl++) { scanL[nl] = s; s += cntL[nl]; }
    }
    __syncthreads();
    if (t < NPB) curL[t] = scanL[t];
    __syncthreads();
    for (int i = t; i < cntB; i += 256) {
        int nl = tnA[base + i] >> 16;
        int loc = atomicAdd(&curL[nl], 1);              // LDS int atomic
        permL[loc] = (ushort_t)i;
    }

    // weight fragments (B-operand layout: col = c+16h, k = q*8+j) — proven layout
    bf16x8 B1[2], B2[2];
    #pragma unroll
    for (int h = 0; h < 2; h++) {
        FU u1, u2;
        #pragma unroll
        for (int j = 0; j < 8; j++) {
            int kk = q * 8 + j, nn = c + 16 * h;
            u1.s[j] = f2bf(w1a[kk * 32 + nn]);
            u2.s[j] = f2bf(w2a[kk * 32 + nn]);
        }
        B1[h] = u1.v; B2[h] = u2.v;
    }
    const float bias1[2] = { b1a[c], b1a[c + 16] };
    const float bias2[2] = { b2a[c], b2a[c + 16] };
    const f32x4 zero = { 0.f, 0.f, 0.f, 0.f };
    __syncthreads();                                    // perm/tgL visible to all waves

    for (int kn = 0; kn < 16; kn++) {
        const int nl = w * 16 + kn;
        const int n  = b * NPB + nl;
        const int startL = scanL[nl], d = cntL[nl];
        float s1a = 0.f, s2a = 0.f, s3a = 0.f, s4a = 0.f;   // feature c
        float s1b = 0.f, s2b = 0.f, s3b = 0.f, s4b = 0.f;   // feature c+16
        const int ntl = (d + 15) >> 4;

        for (int tl = 0; tl < ntl; tl++) {
            int row  = tl * 16 + c;
            int ridx = row < d ? row : d - 1;            // dup rows masked below (d>0 here)
            int li   = permL[startL + ridx];
            FU af;
            if (q < 2) {
                int tg = tgL[li];
                __builtin_memcpy(&af.v, x_tb + (size_t)tg * 16 + q * 8, 16);
            } else {
                __builtin_memcpy(&af.v, eaA + (size_t)(base + li) * 16 + (q - 2) * 8, 16);
            }

            f32x4 a0 = __builtin_amdgcn_mfma_f32_16x16x32_bf16(af.v, B1[0], zero, 0, 0, 0);
            f32x4 a1 = __builtin_amdgcn_mfma_f32_16x16x32_bf16(af.v, B1[1], zero, 0, 0, 0);
            #pragma unroll
            for (int r = 0; r < 4; r++) {
                h_lds[w][q * 4 + r][c]      = leaky(a0[r] + bias1[0], 0.1f);
                h_lds[w][q * 4 + r][c + 16] = leaky(a1[r] + bias1[1], 0.1f);
            }
            __asm__ volatile("s_waitcnt lgkmcnt(0)" ::: "memory");

            float hv[8];
            __builtin_memcpy(&hv, &h_lds[w][c][q * 8], 32);
            FU hf;
            #pragma unroll
            for (int j = 0; j < 8; j++) hf.s[j] = f2bf(hv[j]);
            f32x4 m0 = __builtin_amdgcn_mfma_f32_16x16x32_bf16(hf.v, B2[0], zero, 0, 0, 0);
            f32x4 m1 = __builtin_amdgcn_mfma_f32_16x16x32_bf16(hf.v, B2[1], zero, 0, 0, 0);

            int rb = tl * 16 + q * 4;
            #pragma unroll
            for (int r = 0; r < 4; r++) {
                if (rb + r < d) {
                    float m = m0[r] + bias2[0], mm = m * m;
                    s1a += m;  s2a += mm; s3a += mm * m; s4a += mm * mm;
                    float x = m1[r] + bias2[1], xx = x * x;
                    s1b += x;  s2b += xx; s3b += xx * x; s4b += xx * xx;
                }
            }
            // next tile's h_lds writes ordered after this tile's reads (per-wave in-order DS)
        }

        if (n >= N_NODES) continue;                     // tail bucket: nodes 50000..50047

        s1a += __shfl_xor(s1a, 16); s1a += __shfl_xor(s1a, 32);
        s2a += __shfl_xor(s2a, 16); s2a += __shfl_xor(s2a, 32);
        s3a += __shfl_xor(s3a, 16); s3a += __shfl_xor(s3a, 32);
        s4a += __shfl_xor(s4a, 16); s4a += __shfl_xor(s4a, 32);
        s1b += __shfl_xor(s1b, 16); s1b += __shfl_xor(s1b, 32);
        s2b += __shfl_xor(s2b, 16); s2b += __shfl_xor(s2b, 32);
        s3b += __shfl_xor(s3b, 16); s3b += __shfl_xor(s3b, 32);
        s4b += __shfl_xor(s4b, 16); s4b += __shfl_xor(s4b, 32);

        if (q == 0) {
            float denom = fmaxf((float)d, 1.f);
            {   // feature c
                float mean = s1a / denom, m2r = s2a / denom, m3r = s3a / denom, m4r = s4a / denom;
                float var  = leaky(m2r - mean * mean, 0.01f);
                float stdv = sqrtf(var + 1e-6f);
                float e3   = m3r - 3.f * mean * m2r + 2.f * mean * mean * mean;
                float skew = e3 / (stdv * stdv * stdv);
                float e4   = m4r - 4.f * mean * m3r + 6.f * mean * mean * m2r
                             - 3.f * mean * mean * mean * mean;
                float kurt = e4 / (stdv * stdv * stdv * stdv);
                stat_lds[w][c]      = f2bf(mean);
                stat_lds[w][32 + c] = f2bf(stdv);
                stat_lds[w][64 + c] = f2bf(skew);
                stat_lds[w][96 + c] = f2bf(kurt);
            }
            {   // feature c+16
                float mean = s1b / denom, m2r = s2b / denom, m3r = s3b / denom, m4r = s4b / denom;
                float var  = leaky(m2r - mean * mean, 0.01f);
                float stdv = sqrtf(var + 1e-6f);
                float e3   = m3r - 3.f * mean * m2r + 2.f * mean * mean * mean;
                float skew = e3 / (stdv * stdv * stdv);
                float e4   = m4r - 4.f * mean * m3r + 6.f * mean * mean * m2r
                             - 3.f * mean * mean * mean * mean;
                float kurt = e4 / (stdv * stdv * stdv * stdv);
                stat_lds[w][16 + c]  = f2bf(mean);
                stat_lds[w][48 + c]  = f2bf(stdv);
                stat_lds[w][80 + c]  = f2bf(skew);
                stat_lds[w][112 + c] = f2bf(kurt);
            }
        }
        __asm__ volatile("s_waitcnt lgkmcnt(0)" ::: "memory");

        const size_t basep = (size_t)n * 160;
        unsigned int sv;
        __builtin_memcpy(&sv, &stat_lds[w][L * 2], 4);
        *(unsigned int*)(hcat + basep + 16 + L * 2) = sv;   // coalesced 256 B stats store
        if (L < 16) {
            hcat[basep + L]       = f2bf(x_s[(size_t)n * 16 + L]);
            hcat[basep + 144 + L] = f2bf(u[L]);
        }
    }
}

// ---------------- K5: GEMM1 [N,160]@[160,160] + bias + leaky -> h2 (bf16) ----------------
__global__ __launch_bounds__(256) void k_gemm1(const ushort_t* __restrict__ hcat,
                                               const float* __restrict__ w1b,
                                               const float* __restrict__ b1b,
                                               ushort_t* __restrict__ h2)
{
    __shared__ __align__(16) ushort_t W1T[160 * 168];
    int t = threadIdx.x;
    for (int i = t; i < 160 * 160; i += 256) { int k = i / 160, n = i % 160; W1T[n * 168 + k] = f2bf(w1b[i]); }
    __syncthreads();
    int w = t >> 6, L = t & 63, q = L >> 4, c = L & 15;
    const f32x4 zero = { 0.f, 0.f, 0.f, 0.f };
    for (int tile = blockIdx.x * 4 + w; tile < 3125 * 10; tile += gridDim.x * 4) {
        int rt = tile / 10, nt = tile % 10;
        int m = rt * 16 + c, n = nt * 16 + c;
        f32x4 acc = zero;
        #pragma unroll
        for (int ks = 0; ks < 5; ks++) {
            bf16x8 a; __builtin_memcpy(&a, hcat + (size_t)m * 160 + ks * 32 + q * 8, 16);
            bf16x8 b; __builtin_memcpy(&b, &W1T[n * 168 + ks * 32 + q * 8], 16);
            acc = __builtin_amdgcn_mfma_f32_16x16x32_bf16(a, b, acc, 0, 0, 0);
        }
        float bias = b1b[n];
        #pragma unroll
        for (int r = 0; r < 4; r++) {
            h2[(size_t)(rt * 16 + q * 4 + r) * 160 + n] = f2bf(leaky(acc[r] + bias, 0.1f));
        }
    }
}

// ---------------- K6: GEMM2 [N,160]@[160,16] + bias -> outpre (fp32) + BN partials ----------
__global__ __launch_bounds__(256) void k_gemm2(const ushort_t* __restrict__ h2,
                                               const float* __restrict__ w2b,
                                               const float* __restrict__ b2b,
                                               float* __restrict__ outpre, float* __restrict__ bnsum)
{
    __shared__ __align__(16) ushort_t W2T[16 * 168];
    int t = threadIdx.x;
    for (int i = t; i < 160 * 16; i += 256) { int k = i / 16, n = i % 16; W2T[n * 168 + k] = f2bf(w2b[i]); }
    __syncthreads();
    int w = t >> 6, L = t & 63, q = L >> 4, c = L & 15;
    const f32x4 zero = { 0.f, 0.f, 0.f, 0.f };
    float ps = 0.f, ps2 = 0.f;
    float bias = b2b[c];
    for (int rt = blockIdx.x * 4 + w; rt < 3125; rt += gridDim.x * 4) {
        int m = rt * 16 + c;
        f32x4 acc = zero;
        #pragma unroll
        for (int ks = 0; ks < 5; ks++) {
            bf16x8 a; __builtin_memcpy(&a, h2 + (size_t)m * 160 + ks * 32 + q * 8, 16);
            bf16x8 b; __builtin_memcpy(&b, &W2T[c * 168 + ks * 32 + q * 8], 16);
            acc = __builtin_amdgcn_mfma_f32_16x16x32_bf16(a, b, acc, 0, 0, 0);
        }
        #pragma unroll
        for (int r = 0; r < 4; r++) {
            float v = acc[r] + bias;
            outpre[(size_t)(rt * 16 + q * 4 + r) * 16 + c] = v;
            ps += v; ps2 += v * v;
        }
    }
    ps  += __shfl_xor(ps, 16);  ps  += __shfl_xor(ps, 32);
    ps2 += __shfl_xor(ps2, 16); ps2 += __shfl_xor(ps2, 32);
    if (q == 0) {
        unsafeAtomicAdd(&bnsum[c], ps);
        unsafeAtomicAdd(&bnsum[16 + c], ps2);
    }
}

// ---------------- K7: BatchNorm apply -> d_out (fp32) ----------------
__global__ __launch_bounds__(256) void k_bn(const float* __restrict__ outpre, const float* __restrict__ bnsum,
                                            const float* __restrict__ gamma, const float* __restrict__ beta,
                                            float* __restrict__ out)
{
    int i = blockIdx.x * 256 + threadIdx.x;
    int c = i & 15;
    float x = outpre[i];
    float mu = bnsum[c] * (1.f / N_NODES);
    float var = bnsum[16 + c] * (1.f / N_NODES) - mu * mu;
    out[i] = gamma[c] * (x - mu) * rsqrtf(var + 1e-5f) + beta[c];
}

// ---------------- launch ----------------
extern "C" void kernel_launch(void* const* d_in, const int* in_sizes, int n_in,
                              void* d_out, int out_size, void* d_ws, size_t ws_size,
                              hipStream_t stream) {
    const float* x_s  = (const float*)d_in[0];
    const float* x_t  = (const float*)d_in[1];
    const float* ea   = (const float*)d_in[2];
    const float* u    = (const float*)d_in[3];
    const float* w1a  = (const float*)d_in[4];
    const float* b1a  = (const float*)d_in[5];
    const float* w2a  = (const float*)d_in[6];
    const float* b2a  = (const float*)d_in[7];
    const float* w1b  = (const float*)d_in[8];
    const float* b1b  = (const float*)d_in[9];
    const float* w2b  = (const float*)d_in[10];
    const float* b2b  = (const float*)d_in[11];
    const float* gam  = (const float*)d_in[12];
    const float* bet  = (const float*)d_in[13];
    const int* eidx   = (const int*)d_in[14];
    const int* src = eidx;
    const int* tgt = eidx + N_EDGES;

    char* ws = (char*)d_ws;
    // workspace layout (bytes) — ws_size >= 138,001,536 proven; peak used ~101 MB.
    //   table  [0         ,   613,088)  int[153272]; k_bcount -> scan trio -> k_bscat/k_nodeF
    //   bsum   [  614,400 ,   616,796)  int[599]; scan trio scratch
    //   bnsum  [  655,360 ,   655,488)  float[32]; zeroed in k_scan2
    //   outpre [  786,432 , 3,986,432)  float[800000]
    //   x_tb   [4,194,304 , 5,794,304)  bf16[50000*16]; k_cvtx -> k_nodeF
    //   tnA    [6,291,456 ,12,691,456)  int[1.6M] (tgt | node_local<<16); k_bscat -> k_nodeF
    //   eaA    [16,777,216,67,977,216)  bf16[1.6M*16]; k_bscat -> k_nodeF
    //   hcat   [68,157,440,84,157,440)  bf16[50000*160]; k_nodeF -> k_gemm1
    //   h2     [84,934,656,100,934,656) bf16[50000*160]; k_gemm1 -> k_gemm2
    const size_t OFF_TABLE  = 0;
    const size_t OFF_BSUM   = 614400;
    const size_t OFF_BNSUM  = 655360;
    const size_t OFF_OUTPRE = 786432;
    const size_t OFF_XTB    = 4194304;
    const size_t OFF_TNA    = 6291456;
    const size_t OFF_EAA    = 16777216;
    const size_t OFF_HCAT   = 68157440;
    const size_t OFF_H2     = 84934656;

    int*      table  = (int*)(ws + OFF_TABLE);
    int*      bsum   = (int*)(ws + OFF_BSUM);
    float*    bnsum  = (float*)(ws + OFF_BNSUM);
    float*    outpre = (float*)(ws + OFF_OUTPRE);
    ushort_t* x_tb   = (ushort_t*)(ws + OFF_XTB);
    int*      tnA    = (int*)(ws + OFF_TNA);
    ushort_t* eaA    = (ushort_t*)(ws + OFF_EAA);
    ushort_t* hcat   = (ushort_t*)(ws + OFF_HCAT);
    ushort_t* h2     = (ushort_t*)(ws + OFF_H2);

    k_cvtx  <<<(N_NODES * 16 / 4 + 255) / 256, 256, 0, stream>>>(x_t, x_tb);
    k_bcount<<<NB1, SCATB, 0, stream>>>(src, table);
    k_scan1 <<<NSB, 256, 0, stream>>>(table, bsum);
    k_scan2 <<<1,   256, 0, stream>>>(bsum, bnsum);
    k_scan3 <<<NSB, 256, 0, stream>>>(table, bsum);
    k_bscat <<<NB1, SCATB, 0, stream>>>(src, tgt, ea, table, tnA, eaA);
    k_nodeF <<<NBK, 256, 0, stream>>>(x_tb, eaA, tnA, table, w1a, b1a, w2a, b2a, x_s, u, hcat);
    k_gemm1 <<<1024, 256, 0, stream>>>(hcat, w1b, b1b, h2);
    k_gemm2 <<<512,  256, 0, stream>>>(h2, w2b, b2b, outpre, bnsum);
    k_bn    <<<(N_NODES * 16) / 256, 256, 0, stream>>>(outpre, bnsum, gam, bet, (float*)d_out);
}

// Round 8
// 415.532 us; speedup vs baseline: 4.6952x; 1.0346x over previous
//
#include <hip/hip_runtime.h>

#define N_NODES 50000
#define N_EDGES 1600000

// bucket geometry
#define EPB 8192                          // edges per chunk-block
#define NB1 ((N_EDGES + EPB - 1) / EPB)   // 196 chunks
#define NPB 128                           // nodes per bucket (128: 2x longer scatter runs)
#define NBK ((N_NODES + NPB - 1) / NPB)   // 391 buckets
#define TBL (NBK * NB1)                   // 76636 table entries
#define NSB ((TBL + 255) / 256)           // 300 scan blocks
#define MAXB 4608                         // LDS capacity per bucket (mean 4092, sigma ~64)
#define SCATB 1024                        // k_bcount/k_bscat block size
#define NFT 512                           // k_nodeF threads (8 waves x 16 nodes = 128)

typedef unsigned short ushort_t;
typedef __attribute__((ext_vector_type(8))) __bf16 bf16x8;
typedef __attribute__((ext_vector_type(4))) float  f32x4;

union FU { ushort_t s[8]; bf16x8 v; };

__device__ __forceinline__ ushort_t f2bf(float f) {
    union { float f; unsigned int i; } v; v.f = f;
    unsigned int r = v.i + 0x7fffu + ((v.i >> 16) & 1u);
    return (ushort_t)(r >> 16);
}
__device__ __forceinline__ float leaky(float x, float s) { return x >= 0.f ? x : s * x; }

// ---------------- K1: per-(bucket, chunk) histogram + fused x_t->bf16 convert ----------------
// 196 blocks x 1024 threads = 200704 >= 200000 cvt elements: k_cvtx folded in (saves a dispatch).
__global__ __launch_bounds__(SCATB) void k_bcount(const int* __restrict__ src, int* __restrict__ table,
                                                  const float* __restrict__ x_t, ushort_t* __restrict__ x_tb) {
    __shared__ int cnt[NBK];
    const int t = threadIdx.x, blk = blockIdx.x;
    // fused cvtx: one f32x4 -> 4 bf16 per thread
    const int g = blk * SCATB + t;
    if (g < (N_NODES * 16) / 4) {
        f32x4 v = ((const f32x4*)x_t)[g];
        unsigned long long p = (unsigned long long)f2bf(v[0])
                             | ((unsigned long long)f2bf(v[1]) << 16)
                             | ((unsigned long long)f2bf(v[2]) << 32)
                             | ((unsigned long long)f2bf(v[3]) << 48);
        ((unsigned long long*)x_tb)[g] = p;
    }
    for (int i = t; i < NBK; i += SCATB) cnt[i] = 0;
    __syncthreads();
    const int base = blk * EPB;
    for (int i = t; i < EPB; i += SCATB) {
        int e = base + i;
        if (e < N_EDGES) atomicAdd(&cnt[src[e] >> 7], 1);   // NPB = 128
    }
    __syncthreads();
    for (int b = t; b < NBK; b += SCATB) table[b * NB1 + blk] = cnt[b];
}

// ---------------- K2a/b: hierarchical exclusive scan (scan3 eliminated: consumers add bsum) --
__global__ __launch_bounds__(256) void k_scan1(int* __restrict__ table, int* __restrict__ bsum) {
    __shared__ int buf[256];
    const int t = threadIdx.x, i = blockIdx.x * 256 + t;
    int v = (i < TBL) ? table[i] : 0;
    buf[t] = v; __syncthreads();
    for (int off = 1; off < 256; off <<= 1) {
        int x = (t >= off) ? buf[t - off] : 0;
        __syncthreads(); buf[t] += x; __syncthreads();
    }
    int incl = buf[t];
    if (i < TBL) table[i] = incl - v;                    // block-local exclusive
    if (t == 255) bsum[blockIdx.x] = incl;
}
__global__ __launch_bounds__(256) void k_scan2(int* __restrict__ bsum, float* __restrict__ bnsum) {
    __shared__ int sums[256];
    const int t = threadIdx.x;
    if (t < 32) bnsum[t] = 0.f;
    const int SEG = (NSB + 255) / 256;
    const int s0 = t * SEG, s1 = (s0 + SEG < NSB) ? s0 + SEG : NSB;
    int sum = 0;
    for (int i = s0; i < s1; i++) sum += bsum[i];
    sums[t] = sum; __syncthreads();
    for (int off = 1; off < 256; off <<= 1) {
        int x = (t >= off) ? sums[t - off] : 0;
        __syncthreads(); sums[t] += x; __syncthreads();
    }
    int carry = sums[t] - sum;
    for (int i = s0; i < s1; i++) { int v = bsum[i]; bsum[i] = carry; carry += v; }
}

// ---------------- K3: edge-order record deposit ----------------
// Global position = table[entry] + bsum[entry>>8] (scan3 folded in).
// record = [tgt | node_local<<16] (4 B) + ea bf16 (32 B); runs now ~21 records
// (672 B eaA / 84 B tnA) -> less partial-line write-back than NPB=64's ~10-record runs.
__global__ __launch_bounds__(SCATB) void k_bscat(const int* __restrict__ src, const int* __restrict__ tgt,
                                                 const float* __restrict__ ea, const int* __restrict__ table,
                                                 const int* __restrict__ bsum,
                                                 int* __restrict__ tnA, ushort_t* __restrict__ eaA) {
    __shared__ int cur[NBK];
    const int t = threadIdx.x, blk = blockIdx.x;
    for (int i = t; i < NBK; i += SCATB) {
        int idx = i * NB1 + blk;
        cur[i] = table[idx] + bsum[idx >> 8];
    }
    __syncthreads();
    const int base = blk * EPB;
    for (int i = t; i < EPB; i += SCATB) {
        int e = base + i;
        if (e < N_EDGES) {
            int s = src[e];
            int pos = atomicAdd(&cur[s >> 7], 1);            // LDS int atomic (native)
            tnA[pos] = tgt[e] | ((s & (NPB - 1)) << 16);     // tgt<2^16, nl 7 bits
            const f32x4* ep = (const f32x4*)(ea + (size_t)e * 16);
            f32x4 v0 = __builtin_nontemporal_load(ep);
            f32x4 v1 = __builtin_nontemporal_load(ep + 1);
            f32x4 v2 = __builtin_nontemporal_load(ep + 2);
            f32x4 v3 = __builtin_nontemporal_load(ep + 3);
            FU lo, hi;
            #pragma unroll
            for (int j = 0; j < 4; j++) {
                lo.s[j] = f2bf(v0[j]); lo.s[4 + j] = f2bf(v1[j]);
                hi.s[j] = f2bf(v2[j]); hi.s[4 + j] = f2bf(v3[j]);
            }
            *(bf16x8*)(eaA + (size_t)pos * 16)     = lo.v;
            *(bf16x8*)(eaA + (size_t)pos * 16 + 8) = hi.v;
        }
    }
}

// ---------------- K4: per-bucket node-sort prologue + wave-per-node register moments --------
// 391 blocks x 512 threads (8 waves x 16 nodes = 128 = NPB). Same proven per-wave MFMA
// structure; LDS ~40 KB. Total waves unchanged vs NPB=64 (3128).
__global__ __launch_bounds__(NFT) void k_nodeF(
    const ushort_t* __restrict__ x_tb, const ushort_t* __restrict__ eaA, const int* __restrict__ tnA,
    const int* __restrict__ table, const int* __restrict__ bsum,
    const float* __restrict__ w1a, const float* __restrict__ b1a,
    const float* __restrict__ w2a, const float* __restrict__ b2a,
    const float* __restrict__ x_s, const float* __restrict__ u,
    ushort_t* __restrict__ hcat)
{
    __shared__ ushort_t permL[MAXB];                    // node-sorted local indices
    __shared__ ushort_t tgL[MAXB];                      // tgt per local index
    __shared__ int cntL[NPB], scanL[NPB], curL[NPB];
    __shared__ __align__(16) float h_lds[8][16][36];    // wave-private h slice (proven)
    __shared__ ushort_t stat_lds[8][128];               // wave-private stats staging

    const int t = threadIdx.x;
    const int w = t >> 6, L = t & 63, q = L >> 4, c = L & 15;
    const int b = blockIdx.x;
    const int i0   = b * NB1;
    const int base = table[i0] + bsum[i0 >> 8];
    int end;
    if (b < NBK - 1) { const int i1 = (b + 1) * NB1; end = table[i1] + bsum[i1 >> 8]; }
    else end = N_EDGES;
    const int cntB0 = end - base;
    const int cntB  = cntB0 < MAXB ? cntB0 : MAXB;      // safety clamp (never hit: +8 sigma)

    if (t < NPB) cntL[t] = 0;
    __syncthreads();
    for (int i = t; i < cntB; i += NFT) {
        int v = tnA[base + i];
        tgL[i] = (ushort_t)(v & 0xFFFF);
        atomicAdd(&cntL[v >> 16], 1);                   // LDS int atomic
    }
    __syncthreads();
    if (t == 0) {
        int s = 0;
        for (int nl = 0; nl < NPB; nl++) { scanL[nl] = s; s += cntL[nl]; }
    }
    __syncthreads();
    if (t < NPB) curL[t] = scanL[t];
    __syncthreads();
    for (int i = t; i < cntB; i += NFT) {
        int nl = tnA[base + i] >> 16;
        int loc = atomicAdd(&curL[nl], 1);              // LDS int atomic
        permL[loc] = (ushort_t)i;
    }

    // weight fragments (B-operand layout: col = c+16h, k = q*8+j) — proven layout
    bf16x8 B1[2], B2[2];
    #pragma unroll
    for (int h = 0; h < 2; h++) {
        FU u1, u2;
        #pragma unroll
        for (int j = 0; j < 8; j++) {
            int kk = q * 8 + j, nn = c + 16 * h;
            u1.s[j] = f2bf(w1a[kk * 32 + nn]);
            u2.s[j] = f2bf(w2a[kk * 32 + nn]);
        }
        B1[h] = u1.v; B2[h] = u2.v;
    }
    const float bias1[2] = { b1a[c], b1a[c + 16] };
    const float bias2[2] = { b2a[c], b2a[c + 16] };
    const f32x4 zero = { 0.f, 0.f, 0.f, 0.f };
    __syncthreads();                                    // perm/tgL visible to all waves

    for (int kn = 0; kn < 16; kn++) {
        const int nl = w * 16 + kn;
        const int n  = b * NPB + nl;
        const int startL = scanL[nl], d = cntL[nl];
        float s1a = 0.f, s2a = 0.f, s3a = 0.f, s4a = 0.f;   // feature c
        float s1b = 0.f, s2b = 0.f, s3b = 0.f, s4b = 0.f;   // feature c+16
        const int ntl = (d + 15) >> 4;

        for (int tl = 0; tl < ntl; tl++) {
            int row  = tl * 16 + c;
            int ridx = row < d ? row : d - 1;            // dup rows masked below (d>0 here)
            int li   = permL[startL + ridx];
            FU af;
            if (q < 2) {
                int tg = tgL[li];
                __builtin_memcpy(&af.v, x_tb + (size_t)tg * 16 + q * 8, 16);
            } else {
                __builtin_memcpy(&af.v, eaA + (size_t)(base + li) * 16 + (q - 2) * 8, 16);
            }

            f32x4 a0 = __builtin_amdgcn_mfma_f32_16x16x32_bf16(af.v, B1[0], zero, 0, 0, 0);
            f32x4 a1 = __builtin_amdgcn_mfma_f32_16x16x32_bf16(af.v, B1[1], zero, 0, 0, 0);
            #pragma unroll
            for (int r = 0; r < 4; r++) {
                h_lds[w][q * 4 + r][c]      = leaky(a0[r] + bias1[0], 0.1f);
                h_lds[w][q * 4 + r][c + 16] = leaky(a1[r] + bias1[1], 0.1f);
            }
            __asm__ volatile("s_waitcnt lgkmcnt(0)" ::: "memory");

            float hv[8];
            __builtin_memcpy(&hv, &h_lds[w][c][q * 8], 32);
            FU hf;
            #pragma unroll
            for (int j = 0; j < 8; j++) hf.s[j] = f2bf(hv[j]);
            f32x4 m0 = __builtin_amdgcn_mfma_f32_16x16x32_bf16(hf.v, B2[0], zero, 0, 0, 0);
            f32x4 m1 = __builtin_amdgcn_mfma_f32_16x16x32_bf16(hf.v, B2[1], zero, 0, 0, 0);

            int rb = tl * 16 + q * 4;
            #pragma unroll
            for (int r = 0; r < 4; r++) {
                if (rb + r < d) {
                    float m = m0[r] + bias2[0], mm = m * m;
                    s1a += m;  s2a += mm; s3a += mm * m; s4a += mm * mm;
                    float x = m1[r] + bias2[1], xx = x * x;
                    s1b += x;  s2b += xx; s3b += xx * x; s4b += xx * xx;
                }
            }
            // next tile's h_lds writes ordered after this tile's reads (per-wave in-order DS)
        }

        if (n >= N_NODES) continue;                     // tail bucket: nodes 50000..50047

        s1a += __shfl_xor(s1a, 16); s1a += __shfl_xor(s1a, 32);
        s2a += __shfl_xor(s2a, 16); s2a += __shfl_xor(s2a, 32);
        s3a += __shfl_xor(s3a, 16); s3a += __shfl_xor(s3a, 32);
        s4a += __shfl_xor(s4a, 16); s4a += __shfl_xor(s4a, 32);
        s1b += __shfl_xor(s1b, 16); s1b += __shfl_xor(s1b, 32);
        s2b += __shfl_xor(s2b, 16); s2b += __shfl_xor(s2b, 32);
        s3b += __shfl_xor(s3b, 16); s3b += __shfl_xor(s3b, 32);
        s4b += __shfl_xor(s4b, 16); s4b += __shfl_xor(s4b, 32);

        if (q == 0) {
            float denom = fmaxf((float)d, 1.f);
            {   // feature c
                float mean = s1a / denom, m2r = s2a / denom, m3r = s3a / denom, m4r = s4a / denom;
                float var  = leaky(m2r - mean * mean, 0.01f);
                float stdv = sqrtf(var + 1e-6f);
                float e3   = m3r - 3.f * mean * m2r + 2.f * mean * mean * mean;
                float skew = e3 / (stdv * stdv * stdv);
                float e4   = m4r - 4.f * mean * m3r + 6.f * mean * mean * m2r
                             - 3.f * mean * mean * mean * mean;
                float kurt = e4 / (stdv * stdv * stdv * stdv);
                stat_lds[w][c]      = f2bf(mean);
                stat_lds[w][32 + c] = f2bf(stdv);
                stat_lds[w][64 + c] = f2bf(skew);
                stat_lds[w][96 + c] = f2bf(kurt);
            }
            {   // feature c+16
                float mean = s1b / denom, m2r = s2b / denom, m3r = s3b / denom, m4r = s4b / denom;
                float var  = leaky(m2r - mean * mean, 0.01f);
                float stdv = sqrtf(var + 1e-6f);
                float e3   = m3r - 3.f * mean * m2r + 2.f * mean * mean * mean;
                float skew = e3 / (stdv * stdv * stdv);
                float e4   = m4r - 4.f * mean * m3r + 6.f * mean * mean * m2r
                             - 3.f * mean * mean * mean * mean;
                float kurt = e4 / (stdv * stdv * stdv * stdv);
                stat_lds[w][16 + c]  = f2bf(mean);
                stat_lds[w][48 + c]  = f2bf(stdv);
                stat_lds[w][80 + c]  = f2bf(skew);
                stat_lds[w][112 + c] = f2bf(kurt);
            }
        }
        __asm__ volatile("s_waitcnt lgkmcnt(0)" ::: "memory");

        const size_t basep = (size_t)n * 160;
        unsigned int sv;
        __builtin_memcpy(&sv, &stat_lds[w][L * 2], 4);
        *(unsigned int*)(hcat + basep + 16 + L * 2) = sv;   // coalesced 256 B stats store
        if (L < 16) {
            hcat[basep + L]       = f2bf(x_s[(size_t)n * 16 + L]);
            hcat[basep + 144 + L] = f2bf(u[L]);
        }
    }
}

// ---------------- K5: GEMM1 [N,160]@[160,160] + bias + leaky -> h2 (bf16) ----------------
__global__ __launch_bounds__(256) void k_gemm1(const ushort_t* __restrict__ hcat,
                                               const float* __restrict__ w1b,
                                               const float* __restrict__ b1b,
                                               ushort_t* __restrict__ h2)
{
    __shared__ __align__(16) ushort_t W1T[160 * 168];
    int t = threadIdx.x;
    for (int i = t; i < 160 * 160; i += 256) { int k = i / 160, n = i % 160; W1T[n * 168 + k] = f2bf(w1b[i]); }
    __syncthreads();
    int w = t >> 6, L = t & 63, q = L >> 4, c = L & 15;
    const f32x4 zero = { 0.f, 0.f, 0.f, 0.f };
    for (int tile = blockIdx.x * 4 + w; tile < 3125 * 10; tile += gridDim.x * 4) {
        int rt = tile / 10, nt = tile % 10;
        int m = rt * 16 + c, n = nt * 16 + c;
        f32x4 acc = zero;
        #pragma unroll
        for (int ks = 0; ks < 5; ks++) {
            bf16x8 a; __builtin_memcpy(&a, hcat + (size_t)m * 160 + ks * 32 + q * 8, 16);
            bf16x8 b; __builtin_memcpy(&b, &W1T[n * 168 + ks * 32 + q * 8], 16);
            acc = __builtin_amdgcn_mfma_f32_16x16x32_bf16(a, b, acc, 0, 0, 0);
        }
        float bias = b1b[n];
        #pragma unroll
        for (int r = 0; r < 4; r++) {
            h2[(size_t)(rt * 16 + q * 4 + r) * 160 + n] = f2bf(leaky(acc[r] + bias, 0.1f));
        }
    }
}

// ---------------- K6: GEMM2 [N,160]@[160,16] + bias -> outpre (fp32) + BN partials ----------
__global__ __launch_bounds__(256) void k_gemm2(const ushort_t* __restrict__ h2,
                                               const float* __restrict__ w2b,
                                               const float* __restrict__ b2b,
                                               float* __restrict__ outpre, float* __restrict__ bnsum)
{
    __shared__ __align__(16) ushort_t W2T[16 * 168];
    int t = threadIdx.x;
    for (int i = t; i < 160 * 16; i += 256) { int k = i / 16, n = i % 16; W2T[n * 168 + k] = f2bf(w2b[i]); }
    __syncthreads();
    int w = t >> 6, L = t & 63, q = L >> 4, c = L & 15;
    const f32x4 zero = { 0.f, 0.f, 0.f, 0.f };
    float ps = 0.f, ps2 = 0.f;
    float bias = b2b[c];
    for (int rt = blockIdx.x * 4 + w; rt < 3125; rt += gridDim.x * 4) {
        int m = rt * 16 + c;
        f32x4 acc = zero;
        #pragma unroll
        for (int ks = 0; ks < 5; ks++) {
            bf16x8 a; __builtin_memcpy(&a, h2 + (size_t)m * 160 + ks * 32 + q * 8, 16);
            bf16x8 b; __builtin_memcpy(&b, &W2T[c * 168 + ks * 32 + q * 8], 16);
            acc = __builtin_amdgcn_mfma_f32_16x16x32_bf16(a, b, acc, 0, 0, 0);
        }
        #pragma unroll
        for (int r = 0; r < 4; r++) {
            float v = acc[r] + bias;
            outpre[(size_t)(rt * 16 + q * 4 + r) * 16 + c] = v;
            ps += v; ps2 += v * v;
        }
    }
    ps  += __shfl_xor(ps, 16);  ps  += __shfl_xor(ps, 32);
    ps2 += __shfl_xor(ps2, 16); ps2 += __shfl_xor(ps2, 32);
    if (q == 0) {
        unsafeAtomicAdd(&bnsum[c], ps);
        unsafeAtomicAdd(&bnsum[16 + c], ps2);
    }
}

// ---------------- K7: BatchNorm apply -> d_out (fp32) ----------------
__global__ __launch_bounds__(256) void k_bn(const float* __restrict__ outpre, const float* __restrict__ bnsum,
                                            const float* __restrict__ gamma, const float* __restrict__ beta,
                                            float* __restrict__ out)
{
    int i = blockIdx.x * 256 + threadIdx.x;
    int c = i & 15;
    float x = outpre[i];
    float mu = bnsum[c] * (1.f / N_NODES);
    float var = bnsum[16 + c] * (1.f / N_NODES) - mu * mu;
    out[i] = gamma[c] * (x - mu) * rsqrtf(var + 1e-5f) + beta[c];
}

// ---------------- launch ----------------
extern "C" void kernel_launch(void* const* d_in, const int* in_sizes, int n_in,
                              void* d_out, int out_size, void* d_ws, size_t ws_size,
                              hipStream_t stream) {
    const float* x_s  = (const float*)d_in[0];
    const float* x_t  = (const float*)d_in[1];
    const float* ea   = (const float*)d_in[2];
    const float* u    = (const float*)d_in[3];
    const float* w1a  = (const float*)d_in[4];
    const float* b1a  = (const float*)d_in[5];
    const float* w2a  = (const float*)d_in[6];
    const float* b2a  = (const float*)d_in[7];
    const float* w1b  = (const float*)d_in[8];
    const float* b1b  = (const float*)d_in[9];
    const float* w2b  = (const float*)d_in[10];
    const float* b2b  = (const float*)d_in[11];
    const float* gam  = (const float*)d_in[12];
    const float* bet  = (const float*)d_in[13];
    const int* eidx   = (const int*)d_in[14];
    const int* src = eidx;
    const int* tgt = eidx + N_EDGES;

    char* ws = (char*)d_ws;
    // workspace layout (bytes) — ws_size >= 138,001,536 proven; peak used ~101 MB.
    //   table  [0         ,   306,544)  int[76636]; k_bcount -> k_scan1 -> k_bscat/k_nodeF
    //   bsum   [  614,400 ,   615,600)  int[300]; scan scratch (consumers add bsum[idx>>8])
    //   bnsum  [  655,360 ,   655,488)  float[32]; zeroed in k_scan2
    //   outpre [  786,432 , 3,986,432)  float[800000]
    //   x_tb   [4,194,304 , 5,794,304)  bf16[50000*16]; k_bcount(fused cvtx) -> k_nodeF
    //   tnA    [6,291,456 ,12,691,456)  int[1.6M] (tgt | node_local<<16); k_bscat -> k_nodeF
    //   eaA    [16,777,216,67,977,216)  bf16[1.6M*16]; k_bscat -> k_nodeF
    //   hcat   [68,157,440,84,157,440)  bf16[50000*160]; k_nodeF -> k_gemm1
    //   h2     [84,934,656,100,934,656) bf16[50000*160]; k_gemm1 -> k_gemm2
    const size_t OFF_TABLE  = 0;
    const size_t OFF_BSUM   = 614400;
    const size_t OFF_BNSUM  = 655360;
    const size_t OFF_OUTPRE = 786432;
    const size_t OFF_XTB    = 4194304;
    const size_t OFF_TNA    = 6291456;
    const size_t OFF_EAA    = 16777216;
    const size_t OFF_HCAT   = 68157440;
    const size_t OFF_H2     = 84934656;

    int*      table  = (int*)(ws + OFF_TABLE);
    int*      bsum   = (int*)(ws + OFF_BSUM);
    float*    bnsum  = (float*)(ws + OFF_BNSUM);
    float*    outpre = (float*)(ws + OFF_OUTPRE);
    ushort_t* x_tb   = (ushort_t*)(ws + OFF_XTB);
    int*      tnA    = (int*)(ws + OFF_TNA);
    ushort_t* eaA    = (ushort_t*)(ws + OFF_EAA);
    ushort_t* hcat   = (ushort_t*)(ws + OFF_HCAT);
    ushort_t* h2     = (ushort_t*)(ws + OFF_H2);

    k_bcount<<<NB1, SCATB, 0, stream>>>(src, table, x_t, x_tb);
    k_scan1 <<<NSB, 256, 0, stream>>>(table, bsum);
    k_scan2 <<<1,   256, 0, stream>>>(bsum, bnsum);
    k_bscat <<<NB1, SCATB, 0, stream>>>(src, tgt, ea, table, bsum, tnA, eaA);
    k_nodeF <<<NBK, NFT, 0, stream>>>(x_tb, eaA, tnA, table, bsum, w1a, b1a, w2a, b2a, x_s, u, hcat);
    k_gemm1 <<<1024, 256, 0, stream>>>(hcat, w1b, b1b, h2);
    k_gemm2 <<<512,  256, 0, stream>>>(h2, w2b, b2b, outpre, bnsum);
    k_bn    <<<(N_NODES * 16) / 256, 256, 0, stream>>>(outpre, bnsum, gam, bet, (float*)d_out);
}

// Round 9
// 404.171 us; speedup vs baseline: 4.8272x; 1.0281x over previous
//
#include <hip/hip_runtime.h>

#define N_NODES 50000
#define N_EDGES 1600000

// bucket geometry
#define EPB 8192                          // edges per chunk-block
#define NB1 ((N_EDGES + EPB - 1) / EPB)   // 196 chunks
#define NPB 128                           // nodes per bucket
#define NBK ((N_NODES + NPB - 1) / NPB)   // 391 buckets
#define TBL (NBK * NB1)                   // 76636 table entries
#define NSB ((TBL + 255) / 256)           // 300 scan blocks
#define MAXB 4608                         // LDS capacity per bucket (mean 4092, sigma ~64)
#define SCATB 1024                        // k_bcount/k_bscat block size
#define NFT 512                           // k_nodeF threads (8 waves x 16 nodes = 128)
#define SUBP 2048                         // k_bscat sub-pass edges (LDS record staging)
#define NSUB (EPB / SUBP)                 // 4 sub-passes per chunk

typedef unsigned short ushort_t;
typedef __attribute__((ext_vector_type(8))) __bf16 bf16x8;
typedef __attribute__((ext_vector_type(4))) float  f32x4;

union FU { ushort_t s[8]; bf16x8 v; };

__device__ __forceinline__ ushort_t f2bf(float f) {
    union { float f; unsigned int i; } v; v.f = f;
    unsigned int r = v.i + 0x7fffu + ((v.i >> 16) & 1u);
    return (ushort_t)(r >> 16);
}
__device__ __forceinline__ float leaky(float x, float s) { return x >= 0.f ? x : s * x; }

// ---------------- K1: per-(bucket, chunk) histogram + fused x_t->bf16 convert ----------------
__global__ __launch_bounds__(SCATB) void k_bcount(const int* __restrict__ src, int* __restrict__ table,
                                                  const float* __restrict__ x_t, ushort_t* __restrict__ x_tb) {
    __shared__ int cnt[NBK];
    const int t = threadIdx.x, blk = blockIdx.x;
    // fused cvtx: one f32x4 -> 4 bf16 per thread
    const int g = blk * SCATB + t;
    if (g < (N_NODES * 16) / 4) {
        f32x4 v = ((const f32x4*)x_t)[g];
        unsigned long long p = (unsigned long long)f2bf(v[0])
                             | ((unsigned long long)f2bf(v[1]) << 16)
                             | ((unsigned long long)f2bf(v[2]) << 32)
                             | ((unsigned long long)f2bf(v[3]) << 48);
        ((unsigned long long*)x_tb)[g] = p;
    }
    for (int i = t; i < NBK; i += SCATB) cnt[i] = 0;
    __syncthreads();
    const int base = blk * EPB;
    for (int i = t; i < EPB; i += SCATB) {
        int e = base + i;
        if (e < N_EDGES) atomicAdd(&cnt[src[e] >> 7], 1);   // NPB = 128
    }
    __syncthreads();
    for (int b = t; b < NBK; b += SCATB) table[b * NB1 + blk] = cnt[b];
}

// ---------------- K2a/b: hierarchical exclusive scan (consumers add bsum[idx>>8]) -----------
__global__ __launch_bounds__(256) void k_scan1(int* __restrict__ table, int* __restrict__ bsum) {
    __shared__ int buf[256];
    const int t = threadIdx.x, i = blockIdx.x * 256 + t;
    int v = (i < TBL) ? table[i] : 0;
    buf[t] = v; __syncthreads();
    for (int off = 1; off < 256; off <<= 1) {
        int x = (t >= off) ? buf[t - off] : 0;
        __syncthreads(); buf[t] += x; __syncthreads();
    }
    int incl = buf[t];
    if (i < TBL) table[i] = incl - v;                    // block-local exclusive
    if (t == 255) bsum[blockIdx.x] = incl;
}
__global__ __launch_bounds__(256) void k_scan2(int* __restrict__ bsum, float* __restrict__ bnsum) {
    __shared__ int sums[256];
    const int t = threadIdx.x;
    if (t < 32) bnsum[t] = 0.f;
    const int SEG = (NSB + 255) / 256;
    const int s0 = t * SEG, s1 = (s0 + SEG < NSB) ? s0 + SEG : NSB;
    int sum = 0;
    for (int i = s0; i < s1; i++) sum += bsum[i];
    sums[t] = sum; __syncthreads();
    for (int off = 1; off < 256; off <<= 1) {
        int x = (t >= off) ? sums[t - off] : 0;
        __syncthreads(); sums[t] += x; __syncthreads();
    }
    int carry = sums[t] - sum;
    for (int i = s0; i < s1; i++) { int v = bsum[i]; bsum[i] = carry; carry += v; }
}

// ---------------- K3: LDS-staged rank-and-permute record deposit ----------------
// r8 falsified the run-boundary model: direct scattered 32 B stores leave 1.8x write amp
// regardless of run length (partial-line evictions throughout). Fix: per 2048-edge sub-pass,
// rank edges into bucket-major LDS slots, stage bf16 records in a 64 KB LDS buffer, then a
// WRITE PHASE where consecutive lanes emit consecutive global addresses (full-line stores).
// Global layout identical to before (cursors persist across sub-passes); ea reads sequential.
__global__ __launch_bounds__(SCATB) void k_bscat(const int* __restrict__ src, const int* __restrict__ tgt,
                                                 const float* __restrict__ ea, const int* __restrict__ table,
                                                 const int* __restrict__ bsum,
                                                 int* __restrict__ tnA, ushort_t* __restrict__ eaA) {
    __shared__ int curG[NBK];                 // global cursor per bucket run
    __shared__ int cntL[NBK];                 // per-subpass histogram
    __shared__ int curL[NBK];                 // per-subpass rank cursor
    __shared__ int scanS[512];                // padded in-place scan (exclusive at end)
    __shared__ ushort_t bucketL[SUBP];        // slot -> bucket
    __shared__ __align__(16) ushort_t recbuf[SUBP * 16];   // slot -> 32 B bf16 record (64 KB)

    const int t = threadIdx.x, blk = blockIdx.x;
    for (int i = t; i < NBK; i += SCATB) {
        int idx = i * NB1 + blk;
        curG[i] = table[idx] + bsum[idx >> 8];
        cntL[i] = 0; curL[i] = 0;
    }
    __syncthreads();
    const int cbase = blk * EPB;

    for (int sp = 0; sp < NSUB; sp++) {
        const int sbase = cbase + sp * SUBP;
        const int m = (N_EDGES - sbase < SUBP) ? (N_EDGES - sbase) : SUBP;   // may be <= 0

        // phase 1: histogram
        for (int i = t; i < m; i += SCATB) atomicAdd(&cntL[src[sbase + i] >> 7], 1);
        __syncthreads();
        // phase 2: exclusive scan of cntL (padded Hillis-Steele, all threads hit barriers)
        if (t < 512) scanS[t] = (t < NBK) ? cntL[t] : 0;
        __syncthreads();
        for (int off = 1; off < 512; off <<= 1) {
            int x = (t < 512 && t >= off) ? scanS[t - off] : 0;
            __syncthreads();
            if (t < 512) scanS[t] += x;
            __syncthreads();
        }
        if (t < NBK) scanS[t] -= cntL[t];                 // exclusive
        __syncthreads();
        // phase 3: rank + stage (ea read sequential; record -> LDS slot; tnA direct 4 B)
        for (int i = t; i < m; i += SCATB) {
            int e = sbase + i;
            int s = src[e];
            int b = s >> 7;
            int loc = scanS[b] + atomicAdd(&curL[b], 1);
            bucketL[loc] = (ushort_t)b;
            int gpos = curG[b] + (loc - scanS[b]);
            tnA[gpos] = tgt[e] | ((s & (NPB - 1)) << 16);
            const f32x4* ep = (const f32x4*)(ea + (size_t)e * 16);
            f32x4 v0 = __builtin_nontemporal_load(ep);
            f32x4 v1 = __builtin_nontemporal_load(ep + 1);
            f32x4 v2 = __builtin_nontemporal_load(ep + 2);
            f32x4 v3 = __builtin_nontemporal_load(ep + 3);
            FU lo, hi;
            #pragma unroll
            for (int j = 0; j < 4; j++) {
                lo.s[j] = f2bf(v0[j]); lo.s[4 + j] = f2bf(v1[j]);
                hi.s[j] = f2bf(v2[j]); hi.s[4 + j] = f2bf(v3[j]);
            }
            *(bf16x8*)(recbuf + loc * 16)     = lo.v;
            *(bf16x8*)(recbuf + loc * 16 + 8) = hi.v;
        }
        __syncthreads();
        // phase 4: coalesced emit — consecutive lanes -> consecutive gpos within runs
        for (int loc = t; loc < m; loc += SCATB) {
            int b = bucketL[loc];
            int gpos = curG[b] + (loc - scanS[b]);
            bf16x8 lo = *(bf16x8*)(recbuf + loc * 16);
            bf16x8 hi = *(bf16x8*)(recbuf + loc * 16 + 8);
            *(bf16x8*)(eaA + (size_t)gpos * 16)     = lo;
            *(bf16x8*)(eaA + (size_t)gpos * 16 + 8) = hi;
        }
        __syncthreads();
        // phase 5: advance cursors, reset
        for (int i = t; i < NBK; i += SCATB) {
            curG[i] += cntL[i];
            cntL[i] = 0; curL[i] = 0;
        }
        __syncthreads();
    }
}

// ---------------- K4: per-bucket node-sort prologue + wave-per-node register moments --------
// (unchanged — proven correct)
__global__ __launch_bounds__(NFT) void k_nodeF(
    const ushort_t* __restrict__ x_tb, const ushort_t* __restrict__ eaA, const int* __restrict__ tnA,
    const int* __restrict__ table, const int* __restrict__ bsum,
    const float* __restrict__ w1a, const float* __restrict__ b1a,
    const float* __restrict__ w2a, const float* __restrict__ b2a,
    const float* __restrict__ x_s, const float* __restrict__ u,
    ushort_t* __restrict__ hcat)
{
    __shared__ ushort_t permL[MAXB];                    // node-sorted local indices
    __shared__ ushort_t tgL[MAXB];                      // tgt per local index
    __shared__ int cntL[NPB], scanL[NPB], curL[NPB];
    __shared__ __align__(16) float h_lds[8][16][36];    // wave-private h slice (proven)
    __shared__ ushort_t stat_lds[8][128];               // wave-private stats staging

    const int t = threadIdx.x;
    const int w = t >> 6, L = t & 63, q = L >> 4, c = L & 15;
    const int b = blockIdx.x;
    const int i0   = b * NB1;
    const int base = table[i0] + bsum[i0 >> 8];
    int end;
    if (b < NBK - 1) { const int i1 = (b + 1) * NB1; end = table[i1] + bsum[i1 >> 8]; }
    else end = N_EDGES;
    const int cntB0 = end - base;
    const int cntB  = cntB0 < MAXB ? cntB0 : MAXB;      // safety clamp (never hit: +8 sigma)

    if (t < NPB) cntL[t] = 0;
    __syncthreads();
    for (int i = t; i < cntB; i += NFT) {
        int v = tnA[base + i];
        tgL[i] = (ushort_t)(v & 0xFFFF);
        atomicAdd(&cntL[v >> 16], 1);                   // LDS int atomic
    }
    __syncthreads();
    if (t == 0) {
        int s = 0;
        for (int nl = 0; nl < NPB; nl++) { scanL[nl] = s; s += cntL[nl]; }
    }
    __syncthreads();
    if (t < NPB) curL[t] = scanL[t];
    __syncthreads();
    for (int i = t; i < cntB; i += NFT) {
        int nl = tnA[base + i] >> 16;
        int loc = atomicAdd(&curL[nl], 1);              // LDS int atomic
        permL[loc] = (ushort_t)i;
    }

    // weight fragments (B-operand layout: col = c+16h, k = q*8+j) — proven layout
    bf16x8 B1[2], B2[2];
    #pragma unroll
    for (int h = 0; h < 2; h++) {
        FU u1, u2;
        #pragma unroll
        for (int j = 0; j < 8; j++) {
            int kk = q * 8 + j, nn = c + 16 * h;
            u1.s[j] = f2bf(w1a[kk * 32 + nn]);
            u2.s[j] = f2bf(w2a[kk * 32 + nn]);
        }
        B1[h] = u1.v; B2[h] = u2.v;
    }
    const float bias1[2] = { b1a[c], b1a[c + 16] };
    const float bias2[2] = { b2a[c], b2a[c + 16] };
    const f32x4 zero = { 0.f, 0.f, 0.f, 0.f };
    __syncthreads();                                    // perm/tgL visible to all waves

    for (int kn = 0; kn < 16; kn++) {
        const int nl = w * 16 + kn;
        const int n  = b * NPB + nl;
        const int startL = scanL[nl], d = cntL[nl];
        float s1a = 0.f, s2a = 0.f, s3a = 0.f, s4a = 0.f;   // feature c
        float s1b = 0.f, s2b = 0.f, s3b = 0.f, s4b = 0.f;   // feature c+16
        const int ntl = (d + 15) >> 4;

        for (int tl = 0; tl < ntl; tl++) {
            int row  = tl * 16 + c;
            int ridx = row < d ? row : d - 1;            // dup rows masked below (d>0 here)
            int li   = permL[startL + ridx];
            FU af;
            if (q < 2) {
                int tg = tgL[li];
                __builtin_memcpy(&af.v, x_tb + (size_t)tg * 16 + q * 8, 16);
            } else {
                __builtin_memcpy(&af.v, eaA + (size_t)(base + li) * 16 + (q - 2) * 8, 16);
            }

            f32x4 a0 = __builtin_amdgcn_mfma_f32_16x16x32_bf16(af.v, B1[0], zero, 0, 0, 0);
            f32x4 a1 = __builtin_amdgcn_mfma_f32_16x16x32_bf16(af.v, B1[1], zero, 0, 0, 0);
            #pragma unroll
            for (int r = 0; r < 4; r++) {
                h_lds[w][q * 4 + r][c]      = leaky(a0[r] + bias1[0], 0.1f);
                h_lds[w][q * 4 + r][c + 16] = leaky(a1[r] + bias1[1], 0.1f);
            }
            __asm__ volatile("s_waitcnt lgkmcnt(0)" ::: "memory");

            float hv[8];
            __builtin_memcpy(&hv, &h_lds[w][c][q * 8], 32);
            FU hf;
            #pragma unroll
            for (int j = 0; j < 8; j++) hf.s[j] = f2bf(hv[j]);
            f32x4 m0 = __builtin_amdgcn_mfma_f32_16x16x32_bf16(hf.v, B2[0], zero, 0, 0, 0);
            f32x4 m1 = __builtin_amdgcn_mfma_f32_16x16x32_bf16(hf.v, B2[1], zero, 0, 0, 0);

            int rb = tl * 16 + q * 4;
            #pragma unroll
            for (int r = 0; r < 4; r++) {
                if (rb + r < d) {
                    float m = m0[r] + bias2[0], mm = m * m;
                    s1a += m;  s2a += mm; s3a += mm * m; s4a += mm * mm;
                    float x = m1[r] + bias2[1], xx = x * x;
                    s1b += x;  s2b += xx; s3b += xx * x; s4b += xx * xx;
                }
            }
            // next tile's h_lds writes ordered after this tile's reads (per-wave in-order DS)
        }

        if (n >= N_NODES) continue;                     // tail bucket: nodes 50000..50047

        s1a += __shfl_xor(s1a, 16); s1a += __shfl_xor(s1a, 32);
        s2a += __shfl_xor(s2a, 16); s2a += __shfl_xor(s2a, 32);
        s3a += __shfl_xor(s3a, 16); s3a += __shfl_xor(s3a, 32);
        s4a += __shfl_xor(s4a, 16); s4a += __shfl_xor(s4a, 32);
        s1b += __shfl_xor(s1b, 16); s1b += __shfl_xor(s1b, 32);
        s2b += __shfl_xor(s2b, 16); s2b += __shfl_xor(s2b, 32);
        s3b += __shfl_xor(s3b, 16); s3b += __shfl_xor(s3b, 32);
        s4b += __shfl_xor(s4b, 16); s4b += __shfl_xor(s4b, 32);

        if (q == 0) {
            float denom = fmaxf((float)d, 1.f);
            {   // feature c
                float mean = s1a / denom, m2r = s2a / denom, m3r = s3a / denom, m4r = s4a / denom;
                float var  = leaky(m2r - mean * mean, 0.01f);
                float stdv = sqrtf(var + 1e-6f);
                float e3   = m3r - 3.f * mean * m2r + 2.f * mean * mean * mean;
                float skew = e3 / (stdv * stdv * stdv);
                float e4   = m4r - 4.f * mean * m3r + 6.f * mean * mean * m2r
                             - 3.f * mean * mean * mean * mean;
                float kurt = e4 / (stdv * stdv * stdv * stdv);
                stat_lds[w][c]      = f2bf(mean);
                stat_lds[w][32 + c] = f2bf(stdv);
                stat_lds[w][64 + c] = f2bf(skew);
                stat_lds[w][96 + c] = f2bf(kurt);
            }
            {   // feature c+16
                float mean = s1b / denom, m2r = s2b / denom, m3r = s3b / denom, m4r = s4b / denom;
                float var  = leaky(m2r - mean * mean, 0.01f);
                float stdv = sqrtf(var + 1e-6f);
                float e3   = m3r - 3.f * mean * m2r + 2.f * mean * mean * mean;
                float skew = e3 / (stdv * stdv * stdv);
                float e4   = m4r - 4.f * mean * m3r + 6.f * mean * mean * m2r
                             - 3.f * mean * mean * mean * mean;
                float kurt = e4 / (stdv * stdv * stdv * stdv);
                stat_lds[w][16 + c]  = f2bf(mean);
                stat_lds[w][48 + c]  = f2bf(stdv);
                stat_lds[w][80 + c]  = f2bf(skew);
                stat_lds[w][112 + c] = f2bf(kurt);
            }
        }
        __asm__ volatile("s_waitcnt lgkmcnt(0)" ::: "memory");

        const size_t basep = (size_t)n * 160;
        unsigned int sv;
        __builtin_memcpy(&sv, &stat_lds[w][L * 2], 4);
        *(unsigned int*)(hcat + basep + 16 + L * 2) = sv;   // coalesced 256 B stats store
        if (L < 16) {
            hcat[basep + L]       = f2bf(x_s[(size_t)n * 16 + L]);
            hcat[basep + 144 + L] = f2bf(u[L]);
        }
    }
}

// ---------------- K5: GEMM1 [N,160]@[160,160] + bias + leaky -> h2 (bf16) ----------------
__global__ __launch_bounds__(256) void k_gemm1(const ushort_t* __restrict__ hcat,
                                               const float* __restrict__ w1b,
                                               const float* __restrict__ b1b,
                                               ushort_t* __restrict__ h2)
{
    __shared__ __align__(16) ushort_t W1T[160 * 168];
    int t = threadIdx.x;
    for (int i = t; i < 160 * 160; i += 256) { int k = i / 160, n = i % 160; W1T[n * 168 + k] = f2bf(w1b[i]); }
    __syncthreads();
    int w = t >> 6, L = t & 63, q = L >> 4, c = L & 15;
    const f32x4 zero = { 0.f, 0.f, 0.f, 0.f };
    for (int tile = blockIdx.x * 4 + w; tile < 3125 * 10; tile += gridDim.x * 4) {
        int rt = tile / 10, nt = tile % 10;
        int m = rt * 16 + c, n = nt * 16 + c;
        f32x4 acc = zero;
        #pragma unroll
        for (int ks = 0; ks < 5; ks++) {
            bf16x8 a; __builtin_memcpy(&a, hcat + (size_t)m * 160 + ks * 32 + q * 8, 16);
            bf16x8 b; __builtin_memcpy(&b, &W1T[n * 168 + ks * 32 + q * 8], 16);
            acc = __builtin_amdgcn_mfma_f32_16x16x32_bf16(a, b, acc, 0, 0, 0);
        }
        float bias = b1b[n];
        #pragma unroll
        for (int r = 0; r < 4; r++) {
            h2[(size_t)(rt * 16 + q * 4 + r) * 160 + n] = f2bf(leaky(acc[r] + bias, 0.1f));
        }
    }
}

// ---------------- K6: GEMM2 [N,160]@[160,16] + bias -> outpre (fp32) + BN partials ----------
__global__ __launch_bounds__(256) void k_gemm2(const ushort_t* __restrict__ h2,
                                               const float* __restrict__ w2b,
                                               const float* __restrict__ b2b,
                                               float* __restrict__ outpre, float* __restrict__ bnsum)
{
    __shared__ __align__(16) ushort_t W2T[16 * 168];
    int t = threadIdx.x;
    for (int i = t; i < 160 * 16; i += 256) { int k = i / 16, n = i % 16; W2T[n * 168 + k] = f2bf(w2b[i]); }
    __syncthreads();
    int w = t >> 6, L = t & 63, q = L >> 4, c = L & 15;
    const f32x4 zero = { 0.f, 0.f, 0.f, 0.f };
    float ps = 0.f, ps2 = 0.f;
    float bias = b2b[c];
    for (int rt = blockIdx.x * 4 + w; rt < 3125; rt += gridDim.x * 4) {
        int m = rt * 16 + c;
        f32x4 acc = zero;
        #pragma unroll
        for (int ks = 0; ks < 5; ks++) {
            bf16x8 a; __builtin_memcpy(&a, h2 + (size_t)m * 160 + ks * 32 + q * 8, 16);
            bf16x8 b; __builtin_memcpy(&b, &W2T[c * 168 + ks * 32 + q * 8], 16);
            acc = __builtin_amdgcn_mfma_f32_16x16x32_bf16(a, b, acc, 0, 0, 0);
        }
        #pragma unroll
        for (int r = 0; r < 4; r++) {
            float v = acc[r] + bias;
            outpre[(size_t)(rt * 16 + q * 4 + r) * 16 + c] = v;
            ps += v; ps2 += v * v;
        }
    }
    ps  += __shfl_xor(ps, 16);  ps  += __shfl_xor(ps, 32);
    ps2 += __shfl_xor(ps2, 16); ps2 += __shfl_xor(ps2, 32);
    if (q == 0) {
        unsafeAtomicAdd(&bnsum[c], ps);
        unsafeAtomicAdd(&bnsum[16 + c], ps2);
    }
}

// ---------------- K7: BatchNorm apply -> d_out (fp32) ----------------
__global__ __launch_bounds__(256) void k_bn(const float* __restrict__ outpre, const float* __restrict__ bnsum,
                                            const float* __restrict__ gamma, const float* __restrict__ beta,
                                            float* __restrict__ out)
{
    int i = blockIdx.x * 256 + threadIdx.x;
    int c = i & 15;
    float x = outpre[i];
    float mu = bnsum[c] * (1.f / N_NODES);
    float var = bnsum[16 + c] * (1.f / N_NODES) - mu * mu;
    out[i] = gamma[c] * (x - mu) * rsqrtf(var + 1e-5f) + beta[c];
}

// ---------------- launch ----------------
extern "C" void kernel_launch(void* const* d_in, const int* in_sizes, int n_in,
                              void* d_out, int out_size, void* d_ws, size_t ws_size,
                              hipStream_t stream) {
    const float* x_s  = (const float*)d_in[0];
    const float* x_t  = (const float*)d_in[1];
    const float* ea   = (const float*)d_in[2];
    const float* u    = (const float*)d_in[3];
    const float* w1a  = (const float*)d_in[4];
    const float* b1a  = (const float*)d_in[5];
    const float* w2a  = (const float*)d_in[6];
    const float* b2a  = (const float*)d_in[7];
    const float* w1b  = (const float*)d_in[8];
    const float* b1b  = (const float*)d_in[9];
    const float* w2b  = (const float*)d_in[10];
    const float* b2b  = (const float*)d_in[11];
    const float* gam  = (const float*)d_in[12];
    const float* bet  = (const float*)d_in[13];
    const int* eidx   = (const int*)d_in[14];
    const int* src = eidx;
    const int* tgt = eidx + N_EDGES;

    char* ws = (char*)d_ws;
    // workspace layout (bytes) — ws_size >= 138,001,536 proven; peak used ~101 MB.
    //   table  [0         ,   306,544)  int[76636]; k_bcount -> k_scan1 -> k_bscat/k_nodeF
    //   bsum   [  614,400 ,   615,600)  int[300]; scan scratch (consumers add bsum[idx>>8])
    //   bnsum  [  655,360 ,   655,488)  float[32]; zeroed in k_scan2
    //   outpre [  786,432 , 3,986,432)  float[800000]
    //   x_tb   [4,194,304 , 5,794,304)  bf16[50000*16]; k_bcount(fused cvtx) -> k_nodeF
    //   tnA    [6,291,456 ,12,691,456)  int[1.6M] (tgt | node_local<<16); k_bscat -> k_nodeF
    //   eaA    [16,777,216,67,977,216)  bf16[1.6M*16]; k_bscat -> k_nodeF
    //   hcat   [68,157,440,84,157,440)  bf16[50000*160]; k_nodeF -> k_gemm1
    //   h2     [84,934,656,100,934,656) bf16[50000*160]; k_gemm1 -> k_gemm2
    const size_t OFF_TABLE  = 0;
    const size_t OFF_BSUM   = 614400;
    const size_t OFF_BNSUM  = 655360;
    const size_t OFF_OUTPRE = 786432;
    const size_t OFF_XTB    = 4194304;
    const size_t OFF_TNA    = 6291456;
    const size_t OFF_EAA    = 16777216;
    const size_t OFF_HCAT   = 68157440;
    const size_t OFF_H2     = 84934656;

    int*      table  = (int*)(ws + OFF_TABLE);
    int*      bsum   = (int*)(ws + OFF_BSUM);
    float*    bnsum  = (float*)(ws + OFF_BNSUM);
    float*    outpre = (float*)(ws + OFF_OUTPRE);
    ushort_t* x_tb   = (ushort_t*)(ws + OFF_XTB);
    int*      tnA    = (int*)(ws + OFF_TNA);
    ushort_t* eaA    = (ushort_t*)(ws + OFF_EAA);
    ushort_t* hcat   = (ushort_t*)(ws + OFF_HCAT);
    ushort_t* h2     = (ushort_t*)(ws + OFF_H2);

    k_bcount<<<NB1, SCATB, 0, stream>>>(src, table, x_t, x_tb);
    k_scan1 <<<NSB, 256, 0, stream>>>(table, bsum);
    k_scan2 <<<1,   256, 0, stream>>>(bsum, bnsum);
    k_bscat <<<NB1, SCATB, 0, stream>>>(src, tgt, ea, table, bsum, tnA, eaA);
    k_nodeF <<<NBK, NFT, 0, stream>>>(x_tb, eaA, tnA, table, bsum, w1a, b1a, w2a, b2a, x_s, u, hcat);
    k_gemm1 <<<1024, 256, 0, stream>>>(hcat, w1b, b1b, h2);
    k_gemm2 <<<512,  256, 0, stream>>>(h2, w2b, b2b, outpre, bnsum);
    k_bn    <<<(N_NODES * 16) / 256, 256, 0, stream>>>(outpre, bnsum, gam, bet, (float*)d_out);
}

// Round 10
// 392.334 us; speedup vs baseline: 4.9729x; 1.0302x over previous
//
#include <hip/hip_runtime.h>

#define N_NODES 50000
#define N_EDGES 1600000

// bucket geometry
#define EPB 8192                          // edges per chunk-block
#define NB1 ((N_EDGES + EPB - 1) / EPB)   // 196 chunks
#define NPB 128                           // nodes per bucket
#define NBK ((N_NODES + NPB - 1) / NPB)   // 391 buckets
#define TBL (NBK * NB1)                   // 76636 table entries
#define NSB ((TBL + 255) / 256)           // 300 scan blocks
#define MAXB 4608                         // LDS capacity per bucket (mean 4096, sigma ~64)
#define SCATB 1024                        // k_bcount/k_bscat block size
#define NFT 1024                          // k_nodeF threads (16 waves x 8 nodes = 128 = NPB)
#define SUBP 2048                         // k_bscat sub-pass edges (LDS record staging)
#define NSUB (EPB / SUBP)                 // 4 sub-passes per chunk

typedef unsigned short ushort_t;
typedef __attribute__((ext_vector_type(8))) __bf16 bf16x8;
typedef __attribute__((ext_vector_type(4))) float  f32x4;

union FU { ushort_t s[8]; unsigned int u[4]; bf16x8 v; };

__device__ __forceinline__ ushort_t f2bf(float f) {
    union { float f; unsigned int i; } v; v.f = f;
    unsigned int r = v.i + 0x7fffu + ((v.i >> 16) & 1u);
    return (ushort_t)(r >> 16);
}
// HW packed f32x2 -> bf16x2 (RNE); pure-register VALU asm, replaces 2x 5-op f2bf
__device__ __forceinline__ unsigned int cvtpk(float lo, float hi) {
    unsigned int r;
    asm("v_cvt_pk_bf16_f32 %0, %1, %2" : "=v"(r) : "v"(lo), "v"(hi));
    return r;
}
__device__ __forceinline__ float leaky(float x, float s) { return x >= 0.f ? x : s * x; }

// ---------------- K1: per-(bucket, chunk) histogram + fused x_t->bf16 convert ----------------
__global__ __launch_bounds__(SCATB) void k_bcount(const int* __restrict__ src, int* __restrict__ table,
                                                  const float* __restrict__ x_t, ushort_t* __restrict__ x_tb) {
    __shared__ int cnt[NBK];
    const int t = threadIdx.x, blk = blockIdx.x;
    // fused cvtx: one f32x4 -> 4 bf16 per thread (2 cvt_pk)
    const int g = blk * SCATB + t;
    if (g < (N_NODES * 16) / 4) {
        f32x4 v = ((const f32x4*)x_t)[g];
        unsigned long long p = (unsigned long long)cvtpk(v[0], v[1])
                             | ((unsigned long long)cvtpk(v[2], v[3]) << 32);
        ((unsigned long long*)x_tb)[g] = p;
    }
    for (int i = t; i < NBK; i += SCATB) cnt[i] = 0;
    __syncthreads();
    const int base = blk * EPB;
    for (int i = t; i < EPB; i += SCATB) {
        int e = base + i;
        if (e < N_EDGES) atomicAdd(&cnt[src[e] >> 7], 1);   // NPB = 128
    }
    __syncthreads();
    for (int b = t; b < NBK; b += SCATB) table[b * NB1 + blk] = cnt[b];
}

// ---------------- K2a/b: hierarchical exclusive scan (consumers add bsum[idx>>8]) -----------
__global__ __launch_bounds__(256) void k_scan1(int* __restrict__ table, int* __restrict__ bsum) {
    __shared__ int buf[256];
    const int t = threadIdx.x, i = blockIdx.x * 256 + t;
    int v = (i < TBL) ? table[i] : 0;
    buf[t] = v; __syncthreads();
    for (int off = 1; off < 256; off <<= 1) {
        int x = (t >= off) ? buf[t - off] : 0;
        __syncthreads(); buf[t] += x; __syncthreads();
    }
    int incl = buf[t];
    if (i < TBL) table[i] = incl - v;                    // block-local exclusive
    if (t == 255) bsum[blockIdx.x] = incl;
}
__global__ __launch_bounds__(256) void k_scan2(int* __restrict__ bsum, float* __restrict__ bnsum) {
    __shared__ int sums[256];
    const int t = threadIdx.x;
    if (t < 32) bnsum[t] = 0.f;
    const int SEG = (NSB + 255) / 256;
    const int s0 = t * SEG, s1 = (s0 + SEG < NSB) ? s0 + SEG : NSB;
    int sum = 0;
    for (int i = s0; i < s1; i++) sum += bsum[i];
    sums[t] = sum; __syncthreads();
    for (int off = 1; off < 256; off <<= 1) {
        int x = (t >= off) ? sums[t - off] : 0;
        __syncthreads(); sums[t] += x; __syncthreads();
    }
    int carry = sums[t] - sum;
    for (int i = s0; i < s1; i++) { int v = bsum[i]; bsum[i] = carry; carry += v; }
}

// ---------------- K3: LDS-staged rank-and-permute record deposit (proven r9) ----------------
__global__ __launch_bounds__(SCATB) void k_bscat(const int* __restrict__ src, const int* __restrict__ tgt,
                                                 const float* __restrict__ ea, const int* __restrict__ table,
                                                 const int* __restrict__ bsum,
                                                 int* __restrict__ tnA, ushort_t* __restrict__ eaA) {
    __shared__ int curG[NBK];                 // global cursor per bucket run
    __shared__ int cntL[NBK];                 // per-subpass histogram
    __shared__ int curL[NBK];                 // per-subpass rank cursor
    __shared__ int scanS[512];                // padded in-place scan (exclusive at end)
    __shared__ ushort_t bucketL[SUBP];        // slot -> bucket
    __shared__ __align__(16) ushort_t recbuf[SUBP * 16];   // slot -> 32 B bf16 record (64 KB)

    const int t = threadIdx.x, blk = blockIdx.x;
    for (int i = t; i < NBK; i += SCATB) {
        int idx = i * NB1 + blk;
        curG[i] = table[idx] + bsum[idx >> 8];
        cntL[i] = 0; curL[i] = 0;
    }
    __syncthreads();
    const int cbase = blk * EPB;

    for (int sp = 0; sp < NSUB; sp++) {
        const int sbase = cbase + sp * SUBP;
        const int m = (N_EDGES - sbase < SUBP) ? (N_EDGES - sbase) : SUBP;   // may be <= 0

        // phase 1: histogram
        for (int i = t; i < m; i += SCATB) atomicAdd(&cntL[src[sbase + i] >> 7], 1);
        __syncthreads();
        // phase 2: exclusive scan of cntL (padded Hillis-Steele)
        if (t < 512) scanS[t] = (t < NBK) ? cntL[t] : 0;
        __syncthreads();
        for (int off = 1; off < 512; off <<= 1) {
            int x = (t < 512 && t >= off) ? scanS[t - off] : 0;
            __syncthreads();
            if (t < 512) scanS[t] += x;
            __syncthreads();
        }
        if (t < NBK) scanS[t] -= cntL[t];                 // exclusive
        __syncthreads();
        // phase 3: rank + stage (ea read sequential; record -> LDS slot; tnA direct 4 B)
        for (int i = t; i < m; i += SCATB) {
            int e = sbase + i;
            int s = src[e];
            int b = s >> 7;
            int loc = scanS[b] + atomicAdd(&curL[b], 1);
            bucketL[loc] = (ushort_t)b;
            int gpos = curG[b] + (loc - scanS[b]);
            tnA[gpos] = tgt[e] | ((s & (NPB - 1)) << 16);
            const f32x4* ep = (const f32x4*)(ea + (size_t)e * 16);
            f32x4 v0 = __builtin_nontemporal_load(ep);
            f32x4 v1 = __builtin_nontemporal_load(ep + 1);
            f32x4 v2 = __builtin_nontemporal_load(ep + 2);
            f32x4 v3 = __builtin_nontemporal_load(ep + 3);
            FU lo, hi;
            lo.u[0] = cvtpk(v0[0], v0[1]); lo.u[1] = cvtpk(v0[2], v0[3]);
            lo.u[2] = cvtpk(v1[0], v1[1]); lo.u[3] = cvtpk(v1[2], v1[3]);
            hi.u[0] = cvtpk(v2[0], v2[1]); hi.u[1] = cvtpk(v2[2], v2[3]);
            hi.u[2] = cvtpk(v3[0], v3[1]); hi.u[3] = cvtpk(v3[2], v3[3]);
            *(bf16x8*)(recbuf + loc * 16)     = lo.v;
            *(bf16x8*)(recbuf + loc * 16 + 8) = hi.v;
        }
        __syncthreads();
        // phase 4: coalesced emit — consecutive lanes -> consecutive gpos within runs
        for (int loc = t; loc < m; loc += SCATB) {
            int b = bucketL[loc];
            int gpos = curG[b] + (loc - scanS[b]);
            bf16x8 lo = *(bf16x8*)(recbuf + loc * 16);
            bf16x8 hi = *(bf16x8*)(recbuf + loc * 16 + 8);
            *(bf16x8*)(eaA + (size_t)gpos * 16)     = lo;
            *(bf16x8*)(eaA + (size_t)gpos * 16 + 8) = hi;
        }
        __syncthreads();
        // phase 5: advance cursors, reset
        for (int i = t; i < NBK; i += SCATB) {
            curG[i] += cntL[i];
            cntL[i] = 0; curL[i] = 0;
        }
        __syncthreads();
    }
}

// ---------------- K4: per-bucket node-sort prologue + wave-per-node register moments --------
// r9 diagnosis: 391 blocks x 512 thr = 1.53 blocks/CU -> Occupancy 25%, 2 uneven rounds.
// Now 391 blocks x 1024 thr (16 waves x 8 nodes), LDS ~61 KB -> 2 blocks/CU -> 512 slots >=
// 391: ENTIRE grid co-resident, ~full occupancy, zero extra HBM. tgC compacted by slot
// (was tgL[li]: random-index LDS reads = the 1.49M bank conflicts). cvt_pk replaces f2bf.
__global__ __launch_bounds__(NFT) void k_nodeF(
    const ushort_t* __restrict__ x_tb, const ushort_t* __restrict__ eaA, const int* __restrict__ tnA,
    const int* __restrict__ table, const int* __restrict__ bsum,
    const float* __restrict__ w1a, const float* __restrict__ b1a,
    const float* __restrict__ w2a, const float* __restrict__ b2a,
    const float* __restrict__ x_s, const float* __restrict__ u,
    ushort_t* __restrict__ hcat)
{
    __shared__ ushort_t permL[MAXB];                    // node-sorted local indices (slot-major)
    __shared__ ushort_t tgC[MAXB];                      // tgt per SLOT (coalesced reads)
    __shared__ int cntL[NPB], scanL[NPB], curL[NPB];
    __shared__ __align__(16) float h_lds[16][16][36];   // wave-private h slice (proven)
    __shared__ ushort_t stat_lds[16][128];              // wave-private stats staging

    const int t = threadIdx.x;
    const int w = t >> 6, L = t & 63, q = L >> 4, c = L & 15;
    const int b = blockIdx.x;
    const int i0   = b * NB1;
    const int base = table[i0] + bsum[i0 >> 8];
    int end;
    if (b < NBK - 1) { const int i1 = (b + 1) * NB1; end = table[i1] + bsum[i1 >> 8]; }
    else end = N_EDGES;
    const int cntB0 = end - base;
    const int cntB  = cntB0 < MAXB ? cntB0 : MAXB;      // safety clamp (never hit: +8 sigma)

    if (t < NPB) cntL[t] = 0;
    __syncthreads();
    for (int i = t; i < cntB; i += NFT)
        atomicAdd(&cntL[tnA[base + i] >> 16], 1);       // LDS int atomic
    __syncthreads();
    if (t == 0) {
        int s = 0;
        for (int nl = 0; nl < NPB; nl++) { scanL[nl] = s; s += cntL[nl]; }
    }
    __syncthreads();
    if (t < NPB) curL[t] = scanL[t];
    __syncthreads();
    for (int i = t; i < cntB; i += NFT) {
        int v = tnA[base + i];
        int loc = atomicAdd(&curL[v >> 16], 1);         // LDS int atomic
        permL[loc] = (ushort_t)i;
        tgC[loc]   = (ushort_t)(v & 0xFFFF);
    }

    // weight fragments (B-operand layout: col = c+16h, k = q*8+j) — proven layout
    bf16x8 B1[2], B2[2];
    #pragma unroll
    for (int h = 0; h < 2; h++) {
        FU u1, u2;
        #pragma unroll
        for (int j = 0; j < 8; j++) {
            int kk = q * 8 + j, nn = c + 16 * h;
            u1.s[j] = f2bf(w1a[kk * 32 + nn]);
            u2.s[j] = f2bf(w2a[kk * 32 + nn]);
        }
        B1[h] = u1.v; B2[h] = u2.v;
    }
    const float bias1[2] = { b1a[c], b1a[c + 16] };
    const float bias2[2] = { b2a[c], b2a[c + 16] };
    const f32x4 zero = { 0.f, 0.f, 0.f, 0.f };
    __syncthreads();                                    // perm/tgC visible to all waves

    for (int kn = 0; kn < 8; kn++) {
        const int nl = w * 8 + kn;
        const int n  = b * NPB + nl;
        const int startL = scanL[nl], d = cntL[nl];
        float s1a = 0.f, s2a = 0.f, s3a = 0.f, s4a = 0.f;   // feature c
        float s1b = 0.f, s2b = 0.f, s3b = 0.f, s4b = 0.f;   // feature c+16
        const int ntl = (d + 15) >> 4;

        for (int tl = 0; tl < ntl; tl++) {
            int row  = tl * 16 + c;
            int ridx = row < d ? row : d - 1;            // dup rows masked below (d>0 here)
            int pidx = startL + ridx;
            FU af;
            if (q < 2) {
                int tg = tgC[pidx];                      // slot-indexed: coalesced
                __builtin_memcpy(&af.v, x_tb + (size_t)tg * 16 + q * 8, 16);
            } else {
                int li = permL[pidx];
                __builtin_memcpy(&af.v, eaA + (size_t)(base + li) * 16 + (q - 2) * 8, 16);
            }

            f32x4 a0 = __builtin_amdgcn_mfma_f32_16x16x32_bf16(af.v, B1[0], zero, 0, 0, 0);
            f32x4 a1 = __builtin_amdgcn_mfma_f32_16x16x32_bf16(af.v, B1[1], zero, 0, 0, 0);
            #pragma unroll
            for (int r = 0; r < 4; r++) {
                h_lds[w][q * 4 + r][c]      = leaky(a0[r] + bias1[0], 0.1f);
                h_lds[w][q * 4 + r][c + 16] = leaky(a1[r] + bias1[1], 0.1f);
            }
            __asm__ volatile("s_waitcnt lgkmcnt(0)" ::: "memory");

            float hv[8];
            __builtin_memcpy(&hv, &h_lds[w][c][q * 8], 32);
            FU hf;
            hf.u[0] = cvtpk(hv[0], hv[1]); hf.u[1] = cvtpk(hv[2], hv[3]);
            hf.u[2] = cvtpk(hv[4], hv[5]); hf.u[3] = cvtpk(hv[6], hv[7]);
            f32x4 m0 = __builtin_amdgcn_mfma_f32_16x16x32_bf16(hf.v, B2[0], zero, 0, 0, 0);
            f32x4 m1 = __builtin_amdgcn_mfma_f32_16x16x32_bf16(hf.v, B2[1], zero, 0, 0, 0);

            int rb = tl * 16 + q * 4;
            #pragma unroll
            for (int r = 0; r < 4; r++) {
                if (rb + r < d) {
                    float m = m0[r] + bias2[0], mm = m * m;
                    s1a += m;  s2a += mm; s3a += mm * m; s4a += mm * mm;
                    float x = m1[r] + bias2[1], xx = x * x;
                    s1b += x;  s2b += xx; s3b += xx * x; s4b += xx * xx;
                }
            }
            // next tile's h_lds writes ordered after this tile's reads (per-wave in-order DS)
        }

        if (n >= N_NODES) continue;                     // tail bucket: nodes 50000..50047

        s1a += __shfl_xor(s1a, 16); s1a += __shfl_xor(s1a, 32);
        s2a += __shfl_xor(s2a, 16); s2a += __shfl_xor(s2a, 32);
        s3a += __shfl_xor(s3a, 16); s3a += __shfl_xor(s3a, 32);
        s4a += __shfl_xor(s4a, 16); s4a += __shfl_xor(s4a, 32);
        s1b += __shfl_xor(s1b, 16); s1b += __shfl_xor(s1b, 32);
        s2b += __shfl_xor(s2b, 16); s2b += __shfl_xor(s2b, 32);
        s3b += __shfl_xor(s3b, 16); s3b += __shfl_xor(s3b, 32);
        s4b += __shfl_xor(s4b, 16); s4b += __shfl_xor(s4b, 32);

        if (q == 0) {
            float denom = fmaxf((float)d, 1.f);
            {   // feature c
                float mean = s1a / denom, m2r = s2a / denom, m3r = s3a / denom, m4r = s4a / denom;
                float var  = leaky(m2r - mean * mean, 0.01f);
                float stdv = sqrtf(var + 1e-6f);
                float e3   = m3r - 3.f * mean * m2r + 2.f * mean * mean * mean;
                float skew = e3 / (stdv * stdv * stdv);
                float e4   = m4r - 4.f * mean * m3r + 6.f * mean * mean * m2r
                             - 3.f * mean * mean * mean * mean;
                float kurt = e4 / (stdv * stdv * stdv * stdv);
                stat_lds[w][c]      = f2bf(mean);
                stat_lds[w][32 + c] = f2bf(stdv);
                stat_lds[w][64 + c] = f2bf(skew);
                stat_lds[w][96 + c] = f2bf(kurt);
            }
            {   // feature c+16
                float mean = s1b / denom, m2r = s2b / denom, m3r = s3b / denom, m4r = s4b / denom;
                float var  = leaky(m2r - mean * mean, 0.01f);
                float stdv = sqrtf(var + 1e-6f);
                float e3   = m3r - 3.f * mean * m2r + 2.f * mean * mean * mean;
                float skew = e3 / (stdv * stdv * stdv);
                float e4   = m4r - 4.f * mean * m3r + 6.f * mean * mean * m2r
                             - 3.f * mean * mean * mean * mean;
                float kurt = e4 / (stdv * stdv * stdv * stdv);
                stat_lds[w][16 + c]  = f2bf(mean);
                stat_lds[w][48 + c]  = f2bf(stdv);
                stat_lds[w][80 + c]  = f2bf(skew);
                stat_lds[w][112 + c] = f2bf(kurt);
            }
        }
        __asm__ volatile("s_waitcnt lgkmcnt(0)" ::: "memory");

        const size_t basep = (size_t)n * 160;
        unsigned int sv;
        __builtin_memcpy(&sv, &stat_lds[w][L * 2], 4);
        *(unsigned int*)(hcat + basep + 16 + L * 2) = sv;   // coalesced 256 B stats store
        if (L < 16) {
            hcat[basep + L]       = f2bf(x_s[(size_t)n * 16 + L]);
            hcat[basep + 144 + L] = f2bf(u[L]);
        }
    }
}

// ---------------- K5: GEMM1 [N,160]@[160,160] + bias + leaky -> h2 (bf16) ----------------
__global__ __launch_bounds__(256) void k_gemm1(const ushort_t* __restrict__ hcat,
                                               const float* __restrict__ w1b,
                                               const float* __restrict__ b1b,
                                               ushort_t* __restrict__ h2)
{
    __shared__ __align__(16) ushort_t W1T[160 * 168];
    int t = threadIdx.x;
    for (int i = t; i < 160 * 160; i += 256) { int k = i / 160, n = i % 160; W1T[n * 168 + k] = f2bf(w1b[i]); }
    __syncthreads();
    int w = t >> 6, L = t & 63, q = L >> 4, c = L & 15;
    const f32x4 zero = { 0.f, 0.f, 0.f, 0.f };
    for (int tile = blockIdx.x * 4 + w; tile < 3125 * 10; tile += gridDim.x * 4) {
        int rt = tile / 10, nt = tile % 10;
        int m = rt * 16 + c, n = nt * 16 + c;
        f32x4 acc = zero;
        #pragma unroll
        for (int ks = 0; ks < 5; ks++) {
            bf16x8 a; __builtin_memcpy(&a, hcat + (size_t)m * 160 + ks * 32 + q * 8, 16);
            bf16x8 b; __builtin_memcpy(&b, &W1T[n * 168 + ks * 32 + q * 8], 16);
            acc = __builtin_amdgcn_mfma_f32_16x16x32_bf16(a, b, acc, 0, 0, 0);
        }
        float bias = b1b[n];
        #pragma unroll
        for (int r = 0; r < 4; r++) {
            h2[(size_t)(rt * 16 + q * 4 + r) * 160 + n] = f2bf(leaky(acc[r] + bias, 0.1f));
        }
    }
}

// ---------------- K6: GEMM2 [N,160]@[160,16] + bias -> outpre (fp32) + BN partials ----------
__global__ __launch_bounds__(256) void k_gemm2(const ushort_t* __restrict__ h2,
                                               const float* __restrict__ w2b,
                                               const float* __restrict__ b2b,
                                               float* __restrict__ outpre, float* __restrict__ bnsum)
{
    __shared__ __align__(16) ushort_t W2T[16 * 168];
    int t = threadIdx.x;
    for (int i = t; i < 160 * 16; i += 256) { int k = i / 16, n = i % 16; W2T[n * 168 + k] = f2bf(w2b[i]); }
    __syncthreads();
    int w = t >> 6, L = t & 63, q = L >> 4, c = L & 15;
    const f32x4 zero = { 0.f, 0.f, 0.f, 0.f };
    float ps = 0.f, ps2 = 0.f;
    float bias = b2b[c];
    for (int rt = blockIdx.x * 4 + w; rt < 3125; rt += gridDim.x * 4) {
        int m = rt * 16 + c;
        f32x4 acc = zero;
        #pragma unroll
        for (int ks = 0; ks < 5; ks++) {
            bf16x8 a; __builtin_memcpy(&a, h2 + (size_t)m * 160 + ks * 32 + q * 8, 16);
            bf16x8 b; __builtin_memcpy(&b, &W2T[c * 168 + ks * 32 + q * 8], 16);
            acc = __builtin_amdgcn_mfma_f32_16x16x32_bf16(a, b, acc, 0, 0, 0);
        }
        #pragma unroll
        for (int r = 0; r < 4; r++) {
            float v = acc[r] + bias;
            outpre[(size_t)(rt * 16 + q * 4 + r) * 16 + c] = v;
            ps += v; ps2 += v * v;
        }
    }
    ps  += __shfl_xor(ps, 16);  ps  += __shfl_xor(ps, 32);
    ps2 += __shfl_xor(ps2, 16); ps2 += __shfl_xor(ps2, 32);
    if (q == 0) {
        unsafeAtomicAdd(&bnsum[c], ps);
        unsafeAtomicAdd(&bnsum[16 + c], ps2);
    }
}

// ---------------- K7: BatchNorm apply -> d_out (fp32) ----------------
__global__ __launch_bounds__(256) void k_bn(const float* __restrict__ outpre, const float* __restrict__ bnsum,
                                            const float* __restrict__ gamma, const float* __restrict__ beta,
                                            float* __restrict__ out)
{
    int i = blockIdx.x * 256 + threadIdx.x;
    int c = i & 15;
    float x = outpre[i];
    float mu = bnsum[c] * (1.f / N_NODES);
    float var = bnsum[16 + c] * (1.f / N_NODES) - mu * mu;
    out[i] = gamma[c] * (x - mu) * rsqrtf(var + 1e-5f) + beta[c];
}

// ---------------- launch ----------------
extern "C" void kernel_launch(void* const* d_in, const int* in_sizes, int n_in,
                              void* d_out, int out_size, void* d_ws, size_t ws_size,
                              hipStream_t stream) {
    const float* x_s  = (const float*)d_in[0];
    const float* x_t  = (const float*)d_in[1];
    const float* ea   = (const float*)d_in[2];
    const float* u    = (const float*)d_in[3];
    const float* w1a  = (const float*)d_in[4];
    const float* b1a  = (const float*)d_in[5];
    const float* w2a  = (const float*)d_in[6];
    const float* b2a  = (const float*)d_in[7];
    const float* w1b  = (const float*)d_in[8];
    const float* b1b  = (const float*)d_in[9];
    const float* w2b  = (const float*)d_in[10];
    const float* b2b  = (const float*)d_in[11];
    const float* gam  = (const float*)d_in[12];
    const float* bet  = (const float*)d_in[13];
    const int* eidx   = (const int*)d_in[14];
    const int* src = eidx;
    const int* tgt = eidx + N_EDGES;

    char* ws = (char*)d_ws;
    // workspace layout (bytes) — ws_size >= 138,001,536 proven; peak used ~101 MB.
    //   table  [0         ,   306,544)  int[76636]; k_bcount -> k_scan1 -> k_bscat/k_nodeF
    //   bsum   [  614,400 ,   615,600)  int[300]; scan scratch (consumers add bsum[idx>>8])
    //   bnsum  [  655,360 ,   655,488)  float[32]; zeroed in k_scan2
    //   outpre [  786,432 , 3,986,432)  float[800000]
    //   x_tb   [4,194,304 , 5,794,304)  bf16[50000*16]; k_bcount(fused cvtx) -> k_nodeF
    //   tnA    [6,291,456 ,12,691,456)  int[1.6M] (tgt | node_local<<16); k_bscat -> k_nodeF
    //   eaA    [16,777,216,67,977,216)  bf16[1.6M*16]; k_bscat -> k_nodeF
    //   hcat   [68,157,440,84,157,440)  bf16[50000*160]; k_nodeF -> k_gemm1
    //   h2     [84,934,656,100,934,656) bf16[50000*160]; k_gemm1 -> k_gemm2
    const size_t OFF_TABLE  = 0;
    const size_t OFF_BSUM   = 614400;
    const size_t OFF_BNSUM  = 655360;
    const size_t OFF_OUTPRE = 786432;
    const size_t OFF_XTB    = 4194304;
    const size_t OFF_TNA    = 6291456;
    const size_t OFF_EAA    = 16777216;
    const size_t OFF_HCAT   = 68157440;
    const size_t OFF_H2     = 84934656;

    int*      table  = (int*)(ws + OFF_TABLE);
    int*      bsum   = (int*)(ws + OFF_BSUM);
    float*    bnsum  = (float*)(ws + OFF_BNSUM);
    float*    outpre = (float*)(ws + OFF_OUTPRE);
    ushort_t* x_tb   = (ushort_t*)(ws + OFF_XTB);
    int*      tnA    = (int*)(ws + OFF_TNA);
    ushort_t* eaA    = (ushort_t*)(ws + OFF_EAA);
    ushort_t* hcat   = (ushort_t*)(ws + OFF_HCAT);
    ushort_t* h2     = (ushort_t*)(ws + OFF_H2);

    k_bcount<<<NB1, SCATB, 0, stream>>>(src, table, x_t, x_tb);
    k_scan1 <<<NSB, 256, 0, stream>>>(table, bsum);
    k_scan2 <<<1,   256, 0, stream>>>(bsum, bnsum);
    k_bscat <<<NB1, SCATB, 0, stream>>>(src, tgt, ea, table, bsum, tnA, eaA);
    k_nodeF <<<NBK, NFT, 0, stream>>>(x_tb, eaA, tnA, table, bsum, w1a, b1a, w2a, b2a, x_s, u, hcat);
    k_gemm1 <<<1024, 256, 0, stream>>>(hcat, w1b, b1b, h2);
    k_gemm2 <<<512,  256, 0, stream>>>(h2, w2b, b2b, outpre, bnsum);
    k_bn    <<<(N_NODES * 16) / 256, 256, 0, stream>>>(outpre, bnsum, gam, bet, (float*)d_out);
}

// Round 11
// 388.434 us; speedup vs baseline: 5.0228x; 1.0100x over previous
//
#include <hip/hip_runtime.h>

#define N_NODES 50000
#define N_EDGES 1600000

// bucket geometry
#define EPB 4096                          // edges per chunk-block (391 blocks > 256 CUs)
#define NB1 ((N_EDGES + EPB - 1) / EPB)   // 391 chunks
#define NPB 128                           // nodes per bucket
#define NBK ((N_NODES + NPB - 1) / NPB)   // 391 buckets
#define TBL (NBK * NB1)                   // 152881 table entries
#define NSB ((TBL + 255) / 256)           // 598 scan blocks
#define MAXB 4608                         // LDS capacity per bucket (mean 4092, sigma ~64)
#define SCATB 1024                        // k_bcount/k_bscat block size
#define NFT 1024                          // k_nodeF threads (16 waves x 8 nodes = 128 = NPB)
#define SUBP 2048                         // k_bscat sub-pass edges (LDS record staging)
#define NSUB (EPB / SUBP)                 // 2 sub-passes per chunk

typedef unsigned short ushort_t;
typedef __attribute__((ext_vector_type(8))) __bf16 bf16x8;
typedef __attribute__((ext_vector_type(4))) float  f32x4;

union FU { ushort_t s[8]; unsigned int u[4]; bf16x8 v; };

__device__ __forceinline__ ushort_t f2bf(float f) {
    union { float f; unsigned int i; } v; v.f = f;
    unsigned int r = v.i + 0x7fffu + ((v.i >> 16) & 1u);
    return (ushort_t)(r >> 16);
}
// HW packed f32x2 -> bf16x2 (RNE); pure-register VALU asm
__device__ __forceinline__ unsigned int cvtpk(float lo, float hi) {
    unsigned int r;
    asm("v_cvt_pk_bf16_f32 %0, %1, %2" : "=v"(r) : "v"(lo), "v"(hi));
    return r;
}
__device__ __forceinline__ float leaky(float x, float s) { return x >= 0.f ? x : s * x; }

// ---------------- K1: per-(bucket, chunk) histogram + fused x_t->bf16 convert ----------------
__global__ __launch_bounds__(SCATB) void k_bcount(const int* __restrict__ src, int* __restrict__ table,
                                                  const float* __restrict__ x_t, ushort_t* __restrict__ x_tb) {
    __shared__ int cnt[NBK];
    const int t = threadIdx.x, blk = blockIdx.x;
    // fused cvtx: one f32x4 -> 4 bf16 per thread (2 cvt_pk)
    const int g = blk * SCATB + t;
    if (g < (N_NODES * 16) / 4) {
        f32x4 v = ((const f32x4*)x_t)[g];
        unsigned long long p = (unsigned long long)cvtpk(v[0], v[1])
                             | ((unsigned long long)cvtpk(v[2], v[3]) << 32);
        ((unsigned long long*)x_tb)[g] = p;
    }
    for (int i = t; i < NBK; i += SCATB) cnt[i] = 0;
    __syncthreads();
    const int base = blk * EPB;
    for (int i = t; i < EPB; i += SCATB) {
        int e = base + i;
        if (e < N_EDGES) atomicAdd(&cnt[src[e] >> 7], 1);   // NPB = 128
    }
    __syncthreads();
    for (int b = t; b < NBK; b += SCATB) table[b * NB1 + blk] = cnt[b];
}

// ---------------- K2a/b: hierarchical exclusive scan (consumers add bsum[idx>>8]) -----------
__global__ __launch_bounds__(256) void k_scan1(int* __restrict__ table, int* __restrict__ bsum) {
    __shared__ int buf[256];
    const int t = threadIdx.x, i = blockIdx.x * 256 + t;
    int v = (i < TBL) ? table[i] : 0;
    buf[t] = v; __syncthreads();
    for (int off = 1; off < 256; off <<= 1) {
        int x = (t >= off) ? buf[t - off] : 0;
        __syncthreads(); buf[t] += x; __syncthreads();
    }
    int incl = buf[t];
    if (i < TBL) table[i] = incl - v;                    // block-local exclusive
    if (t == 255) bsum[blockIdx.x] = incl;
}
__global__ __launch_bounds__(256) void k_scan2(int* __restrict__ bsum, float* __restrict__ bnsum) {
    __shared__ int sums[256];
    const int t = threadIdx.x;
    if (t < 32) bnsum[t] = 0.f;
    const int SEG = (NSB + 255) / 256;
    const int s0 = t * SEG, s1 = (s0 + SEG < NSB) ? s0 + SEG : NSB;
    int sum = 0;
    for (int i = s0; i < s1; i++) sum += bsum[i];
    sums[t] = sum; __syncthreads();
    for (int off = 1; off < 256; off <<= 1) {
        int x = (t >= off) ? sums[t - off] : 0;
        __syncthreads(); sums[t] += x; __syncthreads();
    }
    int carry = sums[t] - sum;
    for (int i = s0; i < s1; i++) { int v = bsum[i]; bsum[i] = carry; carry += v; }
}

// ---------------- K3: LDS-staged rank-and-permute record deposit ----------------
// r10 diagnosis: 196 blocks < 256 CUs (idle CUs), 18-barrier Hillis-Steele x4, and 32 B-stride
// recbuf (16-way conflict on b128 emit). Now: 391 blocks (every CU busy), wave-shfl scan
// (3 barriers), recLo/recHi 16 B-stride split (b128 floor). Global layout bit-identical.
__global__ __launch_bounds__(SCATB) void k_bscat(const int* __restrict__ src, const int* __restrict__ tgt,
                                                 const float* __restrict__ ea, const int* __restrict__ table,
                                                 const int* __restrict__ bsum,
                                                 int* __restrict__ tnA, ushort_t* __restrict__ eaA) {
    __shared__ int curG[NBK];                 // global cursor per bucket run
    __shared__ int cntL[NBK];                 // per-subpass histogram
    __shared__ int curL[NBK];                 // per-subpass rank cursor
    __shared__ int scanS[512];                // wave-local exclusive scan
    __shared__ int wtot[8];                   // per-wave totals (exclusive after t0 pass)
    __shared__ ushort_t bucketL[SUBP];        // slot -> bucket
    __shared__ __align__(16) ushort_t recLo[SUBP * 8];   // slot -> bytes [0,16) (32 KB)
    __shared__ __align__(16) ushort_t recHi[SUBP * 8];   // slot -> bytes [16,32) (32 KB)

    const int t = threadIdx.x, blk = blockIdx.x;
    const int wv = t >> 6, ln = t & 63;
    for (int i = t; i < NBK; i += SCATB) {
        int idx = i * NB1 + blk;
        curG[i] = table[idx] + bsum[idx >> 8];
        cntL[i] = 0; curL[i] = 0;
    }
    __syncthreads();
    const int cbase = blk * EPB;

    for (int sp = 0; sp < NSUB; sp++) {
        const int sbase = cbase + sp * SUBP;
        const int m = (N_EDGES - sbase < SUBP) ? (N_EDGES - sbase) : SUBP;   // may be <= 0

        // phase 1: histogram
        for (int i = t; i < m; i += SCATB) atomicAdd(&cntL[src[sbase + i] >> 7], 1);
        __syncthreads();
        // phase 2: exclusive scan of cntL — wave-shfl (no barriers inside), t0 cross-wave
        if (wv < 8) {
            int idx = wv * 64 + ln;
            int v = (idx < NBK) ? cntL[idx] : 0;
            int s = v;
            #pragma unroll
            for (int off = 1; off < 64; off <<= 1) {
                int x = __shfl_up(s, off);
                if (ln >= off) s += x;
            }
            if (ln == 63) wtot[wv] = s;
            scanS[idx] = s - v;                          // wave-local exclusive
        }
        __syncthreads();
        if (t == 0) {
            int s = 0;
            #pragma unroll
            for (int w8 = 0; w8 < 8; w8++) { int v = wtot[w8]; wtot[w8] = s; s += v; }
        }
        __syncthreads();
        // phase 3: rank + stage (ea sequential; record -> LDS slot; tnA direct 4 B)
        for (int i = t; i < m; i += SCATB) {
            int e = sbase + i;
            int s = src[e];
            int b = s >> 7;
            int sb = scanS[b] + wtot[b >> 6];            // global exclusive base
            int loc = sb + atomicAdd(&curL[b], 1);
            bucketL[loc] = (ushort_t)b;
            int gpos = curG[b] + (loc - sb);
            tnA[gpos] = tgt[e] | ((s & (NPB - 1)) << 16);
            const f32x4* ep = (const f32x4*)(ea + (size_t)e * 16);
            f32x4 v0 = __builtin_nontemporal_load(ep);
            f32x4 v1 = __builtin_nontemporal_load(ep + 1);
            f32x4 v2 = __builtin_nontemporal_load(ep + 2);
            f32x4 v3 = __builtin_nontemporal_load(ep + 3);
            FU lo, hi;
            lo.u[0] = cvtpk(v0[0], v0[1]); lo.u[1] = cvtpk(v0[2], v0[3]);
            lo.u[2] = cvtpk(v1[0], v1[1]); lo.u[3] = cvtpk(v1[2], v1[3]);
            hi.u[0] = cvtpk(v2[0], v2[1]); hi.u[1] = cvtpk(v2[2], v2[3]);
            hi.u[2] = cvtpk(v3[0], v3[1]); hi.u[3] = cvtpk(v3[2], v3[3]);
            *(bf16x8*)(recLo + loc * 8) = lo.v;
            *(bf16x8*)(recHi + loc * 8) = hi.v;
        }
        __syncthreads();
        // phase 4: coalesced emit — consecutive lanes -> consecutive gpos within runs
        for (int loc = t; loc < m; loc += SCATB) {
            int b = bucketL[loc];
            int gpos = curG[b] + (loc - (scanS[b] + wtot[b >> 6]));
            bf16x8 lo = *(bf16x8*)(recLo + loc * 8);
            bf16x8 hi = *(bf16x8*)(recHi + loc * 8);
            *(bf16x8*)(eaA + (size_t)gpos * 16)     = lo;
            *(bf16x8*)(eaA + (size_t)gpos * 16 + 8) = hi;
        }
        __syncthreads();
        // phase 5: advance cursors, reset
        for (int i = t; i < NBK; i += SCATB) {
            curG[i] += cntL[i];
            cntL[i] = 0; curL[i] = 0;
        }
        __syncthreads();
    }
}

// ---------------- K4: per-bucket node-sort prologue + wave-per-node register moments --------
// (unchanged from round 10 — proven correct, full-residency geometry)
__global__ __launch_bounds__(NFT) void k_nodeF(
    const ushort_t* __restrict__ x_tb, const ushort_t* __restrict__ eaA, const int* __restrict__ tnA,
    const int* __restrict__ table, const int* __restrict__ bsum,
    const float* __restrict__ w1a, const float* __restrict__ b1a,
    const float* __restrict__ w2a, const float* __restrict__ b2a,
    const float* __restrict__ x_s, const float* __restrict__ u,
    ushort_t* __restrict__ hcat)
{
    __shared__ ushort_t permL[MAXB];                    // node-sorted local indices (slot-major)
    __shared__ ushort_t tgC[MAXB];                      // tgt per SLOT (coalesced reads)
    __shared__ int cntL[NPB], scanL[NPB], curL[NPB];
    __shared__ __align__(16) float h_lds[16][16][36];   // wave-private h slice (proven)
    __shared__ ushort_t stat_lds[16][128];              // wave-private stats staging

    const int t = threadIdx.x;
    const int w = t >> 6, L = t & 63, q = L >> 4, c = L & 15;
    const int b = blockIdx.x;
    const int i0   = b * NB1;
    const int base = table[i0] + bsum[i0 >> 8];
    int end;
    if (b < NBK - 1) { const int i1 = (b + 1) * NB1; end = table[i1] + bsum[i1 >> 8]; }
    else end = N_EDGES;
    const int cntB0 = end - base;
    const int cntB  = cntB0 < MAXB ? cntB0 : MAXB;      // safety clamp (never hit: +8 sigma)

    if (t < NPB) cntL[t] = 0;
    __syncthreads();
    for (int i = t; i < cntB; i += NFT)
        atomicAdd(&cntL[tnA[base + i] >> 16], 1);       // LDS int atomic
    __syncthreads();
    if (t == 0) {
        int s = 0;
        for (int nl = 0; nl < NPB; nl++) { scanL[nl] = s; s += cntL[nl]; }
    }
    __syncthreads();
    if (t < NPB) curL[t] = scanL[t];
    __syncthreads();
    for (int i = t; i < cntB; i += NFT) {
        int v = tnA[base + i];
        int loc = atomicAdd(&curL[v >> 16], 1);         // LDS int atomic
        permL[loc] = (ushort_t)i;
        tgC[loc]   = (ushort_t)(v & 0xFFFF);
    }

    // weight fragments (B-operand layout: col = c+16h, k = q*8+j) — proven layout
    bf16x8 B1[2], B2[2];
    #pragma unroll
    for (int h = 0; h < 2; h++) {
        FU u1, u2;
        #pragma unroll
        for (int j = 0; j < 8; j++) {
            int kk = q * 8 + j, nn = c + 16 * h;
            u1.s[j] = f2bf(w1a[kk * 32 + nn]);
            u2.s[j] = f2bf(w2a[kk * 32 + nn]);
        }
        B1[h] = u1.v; B2[h] = u2.v;
    }
    const float bias1[2] = { b1a[c], b1a[c + 16] };
    const float bias2[2] = { b2a[c], b2a[c + 16] };
    const f32x4 zero = { 0.f, 0.f, 0.f, 0.f };
    __syncthreads();                                    // perm/tgC visible to all waves

    for (int kn = 0; kn < 8; kn++) {
        const int nl = w * 8 + kn;
        const int n  = b * NPB + nl;
        const int startL = scanL[nl], d = cntL[nl];
        float s1a = 0.f, s2a = 0.f, s3a = 0.f, s4a = 0.f;   // feature c
        float s1b = 0.f, s2b = 0.f, s3b = 0.f, s4b = 0.f;   // feature c+16
        const int ntl = (d + 15) >> 4;

        for (int tl = 0; tl < ntl; tl++) {
            int row  = tl * 16 + c;
            int ridx = row < d ? row : d - 1;            // dup rows masked below (d>0 here)
            int pidx = startL + ridx;
            FU af;
            if (q < 2) {
                int tg = tgC[pidx];                      // slot-indexed: coalesced
                __builtin_memcpy(&af.v, x_tb + (size_t)tg * 16 + q * 8, 16);
            } else {
                int li = permL[pidx];
                __builtin_memcpy(&af.v, eaA + (size_t)(base + li) * 16 + (q - 2) * 8, 16);
            }

            f32x4 a0 = __builtin_amdgcn_mfma_f32_16x16x32_bf16(af.v, B1[0], zero, 0, 0, 0);
            f32x4 a1 = __builtin_amdgcn_mfma_f32_16x16x32_bf16(af.v, B1[1], zero, 0, 0, 0);
            #pragma unroll
            for (int r = 0; r < 4; r++) {
                h_lds[w][q * 4 + r][c]      = leaky(a0[r] + bias1[0], 0.1f);
                h_lds[w][q * 4 + r][c + 16] = leaky(a1[r] + bias1[1], 0.1f);
            }
            __asm__ volatile("s_waitcnt lgkmcnt(0)" ::: "memory");

            float hv[8];
            __builtin_memcpy(&hv, &h_lds[w][c][q * 8], 32);
            FU hf;
            hf.u[0] = cvtpk(hv[0], hv[1]); hf.u[1] = cvtpk(hv[2], hv[3]);
            hf.u[2] = cvtpk(hv[4], hv[5]); hf.u[3] = cvtpk(hv[6], hv[7]);
            f32x4 m0 = __builtin_amdgcn_mfma_f32_16x16x32_bf16(hf.v, B2[0], zero, 0, 0, 0);
            f32x4 m1 = __builtin_amdgcn_mfma_f32_16x16x32_bf16(hf.v, B2[1], zero, 0, 0, 0);

            int rb = tl * 16 + q * 4;
            #pragma unroll
            for (int r = 0; r < 4; r++) {
                if (rb + r < d) {
                    float m = m0[r] + bias2[0], mm = m * m;
                    s1a += m;  s2a += mm; s3a += mm * m; s4a += mm * mm;
                    float x = m1[r] + bias2[1], xx = x * x;
                    s1b += x;  s2b += xx; s3b += xx * x; s4b += xx * xx;
                }
            }
            // next tile's h_lds writes ordered after this tile's reads (per-wave in-order DS)
        }

        if (n >= N_NODES) continue;                     // tail bucket: nodes 50000..50047

        s1a += __shfl_xor(s1a, 16); s1a += __shfl_xor(s1a, 32);
        s2a += __shfl_xor(s2a, 16); s2a += __shfl_xor(s2a, 32);
        s3a += __shfl_xor(s3a, 16); s3a += __shfl_xor(s3a, 32);
        s4a += __shfl_xor(s4a, 16); s4a += __shfl_xor(s4a, 32);
        s1b += __shfl_xor(s1b, 16); s1b += __shfl_xor(s1b, 32);
        s2b += __shfl_xor(s2b, 16); s2b += __shfl_xor(s2b, 32);
        s3b += __shfl_xor(s3b, 16); s3b += __shfl_xor(s3b, 32);
        s4b += __shfl_xor(s4b, 16); s4b += __shfl_xor(s4b, 32);

        if (q == 0) {
            float denom = fmaxf((float)d, 1.f);
            {   // feature c
                float mean = s1a / denom, m2r = s2a / denom, m3r = s3a / denom, m4r = s4a / denom;
                float var  = leaky(m2r - mean * mean, 0.01f);
                float stdv = sqrtf(var + 1e-6f);
                float e3   = m3r - 3.f * mean * m2r + 2.f * mean * mean * mean;
                float skew = e3 / (stdv * stdv * stdv);
                float e4   = m4r - 4.f * mean * m3r + 6.f * mean * mean * m2r
                             - 3.f * mean * mean * mean * mean;
                float kurt = e4 / (stdv * stdv * stdv * stdv);
                stat_lds[w][c]      = f2bf(mean);
                stat_lds[w][32 + c] = f2bf(stdv);
                stat_lds[w][64 + c] = f2bf(skew);
                stat_lds[w][96 + c] = f2bf(kurt);
            }
            {   // feature c+16
                float mean = s1b / denom, m2r = s2b / denom, m3r = s3b / denom, m4r = s4b / denom;
                float var  = leaky(m2r - mean * mean, 0.01f);
                float stdv = sqrtf(var + 1e-6f);
                float e3   = m3r - 3.f * mean * m2r + 2.f * mean * mean * mean;
                float skew = e3 / (stdv * stdv * stdv);
                float e4   = m4r - 4.f * mean * m3r + 6.f * mean * mean * m2r
                             - 3.f * mean * mean * mean * mean;
                float kurt = e4 / (stdv * stdv * stdv * stdv);
                stat_lds[w][16 + c]  = f2bf(mean);
                stat_lds[w][48 + c]  = f2bf(stdv);
                stat_lds[w][80 + c]  = f2bf(skew);
                stat_lds[w][112 + c] = f2bf(kurt);
            }
        }
        __asm__ volatile("s_waitcnt lgkmcnt(0)" ::: "memory");

        const size_t basep = (size_t)n * 160;
        unsigned int sv;
        __builtin_memcpy(&sv, &stat_lds[w][L * 2], 4);
        *(unsigned int*)(hcat + basep + 16 + L * 2) = sv;   // coalesced 256 B stats store
        if (L < 16) {
            hcat[basep + L]       = f2bf(x_s[(size_t)n * 16 + L]);
            hcat[basep + 144 + L] = f2bf(u[L]);
        }
    }
}

// ---------------- K5: GEMM1 [N,160]@[160,160] + bias + leaky -> h2 (bf16) ----------------
__global__ __launch_bounds__(256) void k_gemm1(const ushort_t* __restrict__ hcat,
                                               const float* __restrict__ w1b,
                                               const float* __restrict__ b1b,
                                               ushort_t* __restrict__ h2)
{
    __shared__ __align__(16) ushort_t W1T[160 * 168];
    int t = threadIdx.x;
    for (int i = t; i < 160 * 160; i += 256) { int k = i / 160, n = i % 160; W1T[n * 168 + k] = f2bf(w1b[i]); }
    __syncthreads();
    int w = t >> 6, L = t & 63, q = L >> 4, c = L & 15;
    const f32x4 zero = { 0.f, 0.f, 0.f, 0.f };
    for (int tile = blockIdx.x * 4 + w; tile < 3125 * 10; tile += gridDim.x * 4) {
        int rt = tile / 10, nt = tile % 10;
        int m = rt * 16 + c, n = nt * 16 + c;
        f32x4 acc = zero;
        #pragma unroll
        for (int ks = 0; ks < 5; ks++) {
            bf16x8 a; __builtin_memcpy(&a, hcat + (size_t)m * 160 + ks * 32 + q * 8, 16);
            bf16x8 b; __builtin_memcpy(&b, &W1T[n * 168 + ks * 32 + q * 8], 16);
            acc = __builtin_amdgcn_mfma_f32_16x16x32_bf16(a, b, acc, 0, 0, 0);
        }
        float bias = b1b[n];
        #pragma unroll
        for (int r = 0; r < 4; r++) {
            h2[(size_t)(rt * 16 + q * 4 + r) * 160 + n] = f2bf(leaky(acc[r] + bias, 0.1f));
        }
    }
}

// ---------------- K6: GEMM2 [N,160]@[160,16] + bias -> outpre (fp32) + BN partials ----------
__global__ __launch_bounds__(256) void k_gemm2(const ushort_t* __restrict__ h2,
                                               const float* __restrict__ w2b,
                                               const float* __restrict__ b2b,
                                               float* __restrict__ outpre, float* __restrict__ bnsum)
{
    __shared__ __align__(16) ushort_t W2T[16 * 168];
    int t = threadIdx.x;
    for (int i = t; i < 160 * 16; i += 256) { int k = i / 16, n = i % 16; W2T[n * 168 + k] = f2bf(w2b[i]); }
    __syncthreads();
    int w = t >> 6, L = t & 63, q = L >> 4, c = L & 15;
    const f32x4 zero = { 0.f, 0.f, 0.f, 0.f };
    float ps = 0.f, ps2 = 0.f;
    float bias = b2b[c];
    for (int rt = blockIdx.x * 4 + w; rt < 3125; rt += gridDim.x * 4) {
        int m = rt * 16 + c;
        f32x4 acc = zero;
        #pragma unroll
        for (int ks = 0; ks < 5; ks++) {
            bf16x8 a; __builtin_memcpy(&a, h2 + (size_t)m * 160 + ks * 32 + q * 8, 16);
            bf16x8 b; __builtin_memcpy(&b, &W2T[c * 168 + ks * 32 + q * 8], 16);
            acc = __builtin_amdgcn_mfma_f32_16x16x32_bf16(a, b, acc, 0, 0, 0);
        }
        #pragma unroll
        for (int r = 0; r < 4; r++) {
            float v = acc[r] + bias;
            outpre[(size_t)(rt * 16 + q * 4 + r) * 16 + c] = v;
            ps += v; ps2 += v * v;
        }
    }
    ps  += __shfl_xor(ps, 16);  ps  += __shfl_xor(ps, 32);
    ps2 += __shfl_xor(ps2, 16); ps2 += __shfl_xor(ps2, 32);
    if (q == 0) {
        unsafeAtomicAdd(&bnsum[c], ps);
        unsafeAtomicAdd(&bnsum[16 + c], ps2);
    }
}

// ---------------- K7: BatchNorm apply -> d_out (fp32) ----------------
__global__ __launch_bounds__(256) void k_bn(const float* __restrict__ outpre, const float* __restrict__ bnsum,
                                            const float* __restrict__ gamma, const float* __restrict__ beta,
                                            float* __restrict__ out)
{
    int i = blockIdx.x * 256 + threadIdx.x;
    int c = i & 15;
    float x = outpre[i];
    float mu = bnsum[c] * (1.f / N_NODES);
    float var = bnsum[16 + c] * (1.f / N_NODES) - mu * mu;
    out[i] = gamma[c] * (x - mu) * rsqrtf(var + 1e-5f) + beta[c];
}

// ---------------- launch ----------------
extern "C" void kernel_launch(void* const* d_in, const int* in_sizes, int n_in,
                              void* d_out, int out_size, void* d_ws, size_t ws_size,
                              hipStream_t stream) {
    const float* x_s  = (const float*)d_in[0];
    const float* x_t  = (const float*)d_in[1];
    const float* ea   = (const float*)d_in[2];
    const float* u    = (const float*)d_in[3];
    const float* w1a  = (const float*)d_in[4];
    const float* b1a  = (const float*)d_in[5];
    const float* w2a  = (const float*)d_in[6];
    const float* b2a  = (const float*)d_in[7];
    const float* w1b  = (const float*)d_in[8];
    const float* b1b  = (const float*)d_in[9];
    const float* w2b  = (const float*)d_in[10];
    const float* b2b  = (const float*)d_in[11];
    const float* gam  = (const float*)d_in[12];
    const float* bet  = (const float*)d_in[13];
    const int* eidx   = (const int*)d_in[14];
    const int* src = eidx;
    const int* tgt = eidx + N_EDGES;

    char* ws = (char*)d_ws;
    // workspace layout (bytes) — ws_size >= 138,001,536 proven; peak used ~101 MB.
    //   table  [0         ,   611,524)  int[152881]; k_bcount -> k_scan1 -> k_bscat/k_nodeF
    //   bsum   [  614,400 ,   616,792)  int[598]; scan scratch (consumers add bsum[idx>>8])
    //   bnsum  [  655,360 ,   655,488)  float[32]; zeroed in k_scan2
    //   outpre [  786,432 , 3,986,432)  float[800000]
    //   x_tb   [4,194,304 , 5,794,304)  bf16[50000*16]; k_bcount(fused cvtx) -> k_nodeF
    //   tnA    [6,291,456 ,12,691,456)  int[1.6M] (tgt | node_local<<16); k_bscat -> k_nodeF
    //   eaA    [16,777,216,67,977,216)  bf16[1.6M*16]; k_bscat -> k_nodeF
    //   hcat   [68,157,440,84,157,440)  bf16[50000*160]; k_nodeF -> k_gemm1
    //   h2     [84,934,656,100,934,656) bf16[50000*160]; k_gemm1 -> k_gemm2
    const size_t OFF_TABLE  = 0;
    const size_t OFF_BSUM   = 614400;
    const size_t OFF_BNSUM  = 655360;
    const size_t OFF_OUTPRE = 786432;
    const size_t OFF_XTB    = 4194304;
    const size_t OFF_TNA    = 6291456;
    const size_t OFF_EAA    = 16777216;
    const size_t OFF_HCAT   = 68157440;
    const size_t OFF_H2     = 84934656;

    int*      table  = (int*)(ws + OFF_TABLE);
    int*      bsum   = (int*)(ws + OFF_BSUM);
    float*    bnsum  = (float*)(ws + OFF_BNSUM);
    float*    outpre = (float*)(ws + OFF_OUTPRE);
    ushort_t* x_tb   = (ushort_t*)(ws + OFF_XTB);
    int*      tnA    = (int*)(ws + OFF_TNA);
    ushort_t* eaA    = (ushort_t*)(ws + OFF_EAA);
    ushort_t* hcat   = (ushort_t*)(ws + OFF_HCAT);
    ushort_t* h2     = (ushort_t*)(ws + OFF_H2);

    k_bcount<<<NB1, SCATB, 0, stream>>>(src, table, x_t, x_tb);
    k_scan1 <<<NSB, 256, 0, stream>>>(table, bsum);
    k_scan2 <<<1,   256, 0, stream>>>(bsum, bnsum);
    k_bscat <<<NB1, SCATB, 0, stream>>>(src, tgt, ea, table, bsum, tnA, eaA);
    k_nodeF <<<NBK, NFT, 0, stream>>>(x_tb, eaA, tnA, table, bsum, w1a, b1a, w2a, b2a, x_s, u, hcat);
    k_gemm1 <<<1024, 256, 0, stream>>>(hcat, w1b, b1b, h2);
    k_gemm2 <<<512,  256, 0, stream>>>(h2, w2b, b2b, outpre, bnsum);
    k_bn    <<<(N_NODES * 16) / 256, 256, 0, stream>>>(outpre, bnsum, gam, bet, (float*)d_out);
}